// Round 5
// baseline (275.507 us; speedup 1.0000x reference)
//
#include <hip/hip_runtime.h>
#include <hip/hip_bf16.h>
#include <math.h>

// SAM2 MultiScale Block — round 12: mlp split-k hidden buffer.
//  - hid_s halved ([32][456], channels in 2 phases of 448) -> LDS 72.7K->44.0K
//    -> 3 blocks/CU (24 waves/CU). GEMM2 accumulates across phases in a single
//    f32x16 (16 VGPR live across GEMM1 phase B). launch_bounds(512,6).
//  - barriers 2 -> 4; GEMM1 per-phase NT=2/1 (waves {2x6,1x2} tiles).
// ln1/attn/aproj/respool/cast identical to R11.
// DIM=112(K pad 128), DIM_OUT=224, HEADS=4, HD=56, WS=8, QS=2, MLP=896
//
// ws layout (bytes):
//   hs_bf @ 0          : 131072x112 bf16 = 29,360,128
//   hs2   @ 29,360,128 : 32768x224 f32   = 29,360,128
//   o_bf  @ 58,720,256 : 32768x224 bf16  = 14,680,064
//   wF    @ 73,400,320 : frag-packed bf16 weights (elems):
//     qkvF 704x128 @ +0       rpF 224x128 @ +90112   apF 224x224 @ +118784
//     m1F  896x224 @ +168960  m2F 224x896 @ +369664  (end 570368)
// 16x16 frag order (qkvF/rpF/apF): (n,k) -> tile=(n/16)*KT+(k/32);
//   flat=(tile*64+lane)*8+j, lane=((k%32)/8)*16+(n%16), j=k%8.
// 32x32 frag order (m1F/m2F): (n,k) -> tile=(n/32)*KT16+(k/16);
//   flat=(tile*64+lane)*8+j, lane=((k%16)/8)*32+(n%32), j=k%8.

#define SCALE_A 0.13363062095621219f  // 56^-0.5

typedef __attribute__((ext_vector_type(8))) short short8;
typedef __attribute__((ext_vector_type(4))) short short4v;
typedef __attribute__((ext_vector_type(4))) float f32x4;
typedef __attribute__((ext_vector_type(16))) float f32x16;

__device__ inline short f2bf(float x) {
  union { float f; unsigned u; } v; v.f = x;
  unsigned r = v.u + 0x7fff + ((v.u >> 16) & 1);
  return (short)(r >> 16);
}
// sigmoid-form tanh-GELU: x * sigmoid(1.59576912*(x + 0.044715 x^3)).
__device__ inline float gelu_fast(float x) {
  float x2 = x * x;
  float p = fmaf(x2, 0.044715f, 1.0f);
  float t = -1.5957691216057308f * x * p;
  return x / (1.0f + __expf(t));
}

// ------------------------------------------- weight cast to frag order
__global__ void cast_w_kernel(const float* __restrict__ qkv_w,
                              const float* __restrict__ rp_w,
                              const float* __restrict__ ap_w,
                              const float* __restrict__ m1_w,
                              const float* __restrict__ m2_w,
                              short* __restrict__ wF) {
  int tid = blockIdx.x * blockDim.x + threadIdx.x;
  int stride = gridDim.x * blockDim.x;
  // qkvF: permuted cols cp = h*176 + cl; cl: [q 0..55|k 56..111|v 112..167|pad]
  for (int e = tid; e < 90112; e += stride) {
    int j = e & 7, lr = (e >> 3) & 15, lqq = (e >> 7) & 3, tile = e >> 9;
    int kt = tile & 3, nt = tile >> 2;
    int cp = nt * 16 + lr;
    int h = cp / 176, cl = cp % 176;
    int k = kt * 32 + lqq * 8 + j;
    float val = 0.f;
    if (k < 112 && cl < 168) {
      int bcol = (cl < 56) ? (h * 56 + cl)
               : (cl < 112) ? (224 + h * 56 + (cl - 56))
                            : (448 + h * 56 + (cl - 112));
      val = qkv_w[k * 672 + bcol];
    }
    wF[e] = f2bf(val);
  }
  for (int e = tid; e < 28672; e += stride) {  // rpF: N=224, KT=4 (16x16)
    int j = e & 7, lr = (e >> 3) & 15, lqq = (e >> 7) & 3, tile = e >> 9;
    int kt = tile & 3, nt = tile >> 2;
    int n = nt * 16 + lr, k = kt * 32 + lqq * 8 + j;
    wF[90112 + e] = (k < 112) ? f2bf(rp_w[k * 224 + n]) : (short)0;
  }
  for (int e = tid; e < 50176; e += stride) {  // apF: N=224, KT=7 (16x16)
    int j = e & 7, lr = (e >> 3) & 15, lqq = (e >> 7) & 3, tile = e >> 9;
    int kt = tile % 7, nt = tile / 7;
    int n = nt * 16 + lr, k = kt * 32 + lqq * 8 + j;
    wF[118784 + e] = f2bf(ap_w[k * 224 + n]);
  }
  for (int e = tid; e < 200704; e += stride) {  // m1F: N=896/32, K=224/16 (32x32)
    int j = e & 7, lane = (e >> 3) & 63, unit = e >> 9;
    int kt = unit % 14, nt = unit / 14;
    int n = nt * 32 + (lane & 31), k = kt * 16 + (lane >> 5) * 8 + j;
    wF[168960 + e] = f2bf(m1_w[k * 896 + n]);
  }
  for (int e = tid; e < 200704; e += stride) {  // m2F: N=224/32, K=896/16 (32x32)
    int j = e & 7, lane = (e >> 3) & 63, unit = e >> 9;
    int kt = unit % 56, nt = unit / 56;
    int n = nt * 32 + (lane & 31), k = kt * 16 + (lane >> 5) * 8 + j;
    wF[369664 + e] = f2bf(m2_w[k * 224 + n]);
  }
}

// ---------------------------------------------------------------- LN1 -> bf16
// R11: 2 rows/wave, f32x4 loads (lanes 0..27 of each 32-half), shfl_xor(32)
// reduce, short4 bf16 stores. 8 rows/block, 16384 blocks.
__global__ __launch_bounds__(256) void ln1_kernel(
    const float* __restrict__ x, const float* __restrict__ g,
    const float* __restrict__ b, short* __restrict__ hs) {
  int wave = threadIdx.x >> 6, lane = threadIdx.x & 63;
  int half = lane >> 5, sub = lane & 31;
  size_t row = (size_t)blockIdx.x * 8 + wave * 2 + half;
  const float* rp = x + row * 112;
  f32x4 v = {0.f, 0.f, 0.f, 0.f};
  if (sub < 28) v = *(const f32x4*)(rp + sub * 4);
  float s = v[0] + v[1] + v[2] + v[3];
  #pragma unroll
  for (int off = 16; off; off >>= 1) s += __shfl_xor(s, off, 32);
  float mean = s * (1.f / 112.f);
  float s2 = 0.f;
  #pragma unroll
  for (int q = 0; q < 4; ++q) { float d = v[q] - mean; s2 = fmaf(d, d, s2); }
  if (sub >= 28) s2 = 0.f;
  #pragma unroll
  for (int off = 16; off; off >>= 1) s2 += __shfl_xor(s2, off, 32);
  float rs = rsqrtf(s2 * (1.f / 112.f) + 1e-6f);
  if (sub < 28) {
    f32x4 gg = *(const f32x4*)(g + sub * 4);
    f32x4 bb = *(const f32x4*)(b + sub * 4);
    short4v o;
    #pragma unroll
    for (int q = 0; q < 4; ++q)
      o[q] = f2bf((v[q] - mean) * rs * gg[q] + bb[q]);
    *(short4v*)(hs + row * 112 + sub * 4) = o;
  }
}

// -------------------------------------- res_proj + maxpool2 (MFMA) -> hs2
__global__ __launch_bounds__(256, 8) void respool_kernel(
    const short* __restrict__ hs, const short* __restrict__ rpF,
    const float* __restrict__ bias, float* __restrict__ hs2) {
  __shared__ alignas(16) short w_s[64 * 136];
  int blk = blockIdx.x;  // 2048
  int tid = threadIdx.x;
  for (int e = tid; e < 1024; e += 256) {
    int m = e >> 4, c = e & 15;
    short8* dst = (short8*)&w_s[m * 136 + c * 8];
    if (c < 14) {
      int p = m >> 2, r = m & 3;
      int pix = blk * 16 + p;
      int bb = pix >> 12, ii = (pix >> 6) & 63, jj = pix & 63;
      size_t token = ((size_t)(bb * 128 + 2 * ii + (r >> 1))) * 128 + 2 * jj + (r & 1);
      *dst = *(const short8*)(hs + token * 112 + c * 8);
    } else {
      short8 z = {0, 0, 0, 0, 0, 0, 0, 0};
      *dst = z;
    }
  }
  __syncthreads();
  int wave = tid >> 6, lane = tid & 63, lrow = lane & 15, lq = lane >> 4;
  short8 Ar[4];
  #pragma unroll
  for (int kt = 0; kt < 4; ++kt)
    Ar[kt] = *(const short8*)&w_s[(wave * 16 + lrow) * 136 + kt * 32 + lq * 8];
  int p = wave * 4 + lq;
  for (int pr = 0; pr < 7; ++pr) {
    int c0 = pr * 32 + lrow, c1 = c0 + 16;
    f32x4 acc0 = {0.f, 0.f, 0.f, 0.f}, acc1 = {0.f, 0.f, 0.f, 0.f};
    #pragma unroll
    for (int kt = 0; kt < 4; ++kt) {
      short8 b0 = *(const short8*)(rpF + (((2 * pr) * 4 + kt) * 64 + lane) * 8);
      short8 b1 = *(const short8*)(rpF + (((2 * pr + 1) * 4 + kt) * 64 + lane) * 8);
      acc0 = __builtin_amdgcn_mfma_f32_16x16x32_bf16(Ar[kt], b0, acc0, 0, 0, 0);
      acc1 = __builtin_amdgcn_mfma_f32_16x16x32_bf16(Ar[kt], b1, acc1, 0, 0, 0);
    }
    float m0 = fmaxf(fmaxf(acc0[0], acc0[1]), fmaxf(acc0[2], acc0[3])) + bias[c0];
    float m1 = fmaxf(fmaxf(acc1[0], acc1[1]), fmaxf(acc1[2], acc1[3])) + bias[c1];
    hs2[(size_t)(blk * 16 + p) * 224 + c0] = m0;
    hs2[(size_t)(blk * 16 + p) * 224 + c1] = m1;
  }
}

// ------------------- fused windowed attention, round 9: head-per-wave
__global__ __launch_bounds__(256, 2) void attn_kernel(
    const short* __restrict__ hs, const short* __restrict__ qkvF,
    const float* __restrict__ qkv_b, short* __restrict__ o_bf) {
  __shared__ alignas(16) short u_s[4 * 9792];   // 78,336 B
  int win = blockIdx.x;                         // 2048
  int nw = win & 15, nh = (win >> 4) & 15, b = win >> 8;
  int tid = threadIdx.x;
  int wave = tid >> 6, lane = tid & 63, lrow = lane & 15, lq = lane >> 4;
  short* w_s  = u_s;                    // [64*136] staging (union, hoist only)
  short* k_s  = u_s + wave * 9792;      // private
  short* vT_s = k_s + 4608;
  short* qp_s = k_s + 8640;

  for (int e = tid; e < 1024; e += 256) {
    int m = e >> 4, c = e & 15;
    short8* dst = (short8*)&w_s[m * 136 + c * 8];
    if (c < 14) {
      int p = m >> 2, r = m & 3;
      int tr = (p >> 2) * 2 + (r >> 1), tc = (p & 3) * 2 + (r & 1);
      size_t token = ((size_t)(b * 128 + nh * 8 + tr)) * 128 + (nw * 8 + tc);
      *dst = *(const short8*)(hs + token * 112 + c * 8);
    } else {
      short8 z = {0, 0, 0, 0, 0, 0, 0, 0};
      *dst = z;
    }
  }
  __syncthreads();  // staging done

  // hoist A-frags for all 4 M-tiles: 64 VGPR
  short8 Aw[4][4];
  #pragma unroll
  for (int mt = 0; mt < 4; ++mt)
    #pragma unroll
    for (int kt = 0; kt < 4; ++kt)
      Aw[mt][kt] = *(const short8*)&w_s[(mt * 16 + lrow) * 136 + kt * 32 + lq * 8];
  __syncthreads();  // hoists done; per-wave regions may be written

  // zero pads (per-wave, one short8 store per lane)
  {
    short8 z = {0, 0, 0, 0, 0, 0, 0, 0};
    *(short8*)&k_s[lane * 72 + 56] = z;          // k pad cols 56..63, 64 rows
    if (lane < 16) *(short8*)&qp_s[lane * 72 + 56] = z;  // q pad
  }

  int h = wave;  // head ownership

  // ---- qkv: 11 N-tiles for this head, all 4 M-tiles
  #pragma unroll 2
  for (int t = 0; t < 11; ++t) {
    int cl = t * 16 + lrow;
    f32x4 ac[4] = {{0.f,0.f,0.f,0.f},{0.f,0.f,0.f,0.f},
                   {0.f,0.f,0.f,0.f},{0.f,0.f,0.f,0.f}};
    short8 bw[4];
    #pragma unroll
    for (int kt = 0; kt < 4; ++kt)
      bw[kt] = *(const short8*)(qkvF + (((h * 11 + t) * 4 + kt) * 64 + lane) * 8);
    #pragma unroll
    for (int kt = 0; kt < 4; ++kt)
      #pragma unroll
      for (int mt = 0; mt < 4; ++mt)
        ac[mt] = __builtin_amdgcn_mfma_f32_16x16x32_bf16(Aw[mt][kt], bw[kt], ac[mt], 0, 0, 0);
    if (cl < 56) {
      float bias = qkv_b[h * 56 + cl];
      #pragma unroll
      for (int mt = 0; mt < 4; ++mt) {
        float mx = fmaxf(fmaxf(ac[mt][0], ac[mt][1]),
                         fmaxf(ac[mt][2], ac[mt][3])) + bias;
        qp_s[(mt * 4 + lq) * 72 + cl] = f2bf(mx * SCALE_A);
      }
    } else if (cl < 112) {
      float bias = qkv_b[224 + h * 56 + (cl - 56)];
      #pragma unroll
      for (int mt = 0; mt < 4; ++mt)
        #pragma unroll
        for (int r = 0; r < 4; ++r)
          k_s[(mt * 16 + lq * 4 + r) * 72 + (cl - 56)] = f2bf(ac[mt][r] + bias);
    } else if (cl < 168) {
      float bias = qkv_b[448 + h * 56 + (cl - 112)];
      #pragma unroll
      for (int mt = 0; mt < 4; ++mt) {
        short4v pk = {f2bf(ac[mt][0] + bias), f2bf(ac[mt][1] + bias),
                      f2bf(ac[mt][2] + bias), f2bf(ac[mt][3] + bias)};
        *(short4v*)&vT_s[(cl - 112) * 72 + mt * 16 + lq * 4] = pk;
      }
    }
  }
  // no barrier: same-wave LDS write->read (waitcnt handles it)

  // ---- scores: 16 queries x 64 keys
  short8 aq[2];
  #pragma unroll
  for (int kt = 0; kt < 2; ++kt)
    aq[kt] = *(const short8*)&qp_s[lrow * 72 + kt * 32 + lq * 8];
  f32x4 sc[4];
  #pragma unroll
  for (int t = 0; t < 4; ++t) {
    sc[t][0] = sc[t][1] = sc[t][2] = sc[t][3] = 0.f;
    #pragma unroll
    for (int kt = 0; kt < 2; ++kt) {
      short8 bk = *(const short8*)&k_s[(t * 16 + lrow) * 72 + kt * 32 + lq * 8];
      sc[t] = __builtin_amdgcn_mfma_f32_16x16x32_bf16(aq[kt], bk, sc[t], 0, 0, 0);
    }
  }
  // ---- softmax rows lq*4+r: reduce over t (local) and lrow (16-lane shfl)
  float mr[4], sr[4];
  #pragma unroll
  for (int r = 0; r < 4; ++r)
    mr[r] = fmaxf(fmaxf(sc[0][r], sc[1][r]), fmaxf(sc[2][r], sc[3][r]));
  #pragma unroll
  for (int off = 8; off; off >>= 1)
    #pragma unroll
    for (int r = 0; r < 4; ++r) mr[r] = fmaxf(mr[r], __shfl_xor(mr[r], off, 16));
  #pragma unroll
  for (int r = 0; r < 4; ++r) {
    #pragma unroll
    for (int t = 0; t < 4; ++t) sc[t][r] = __expf(sc[t][r] - mr[r]);
    sr[r] = sc[0][r] + sc[1][r] + sc[2][r] + sc[3][r];
  }
  #pragma unroll
  for (int off = 8; off; off >>= 1)
    #pragma unroll
    for (int r = 0; r < 4; ++r) sr[r] += __shfl_xor(sr[r], off, 16);
  #pragma unroll
  for (int r = 0; r < 4; ++r) sr[r] = 1.f / sr[r];
  // normalized P -> qp_s (q is dead; same-wave write->read, no barrier)
  #pragma unroll
  for (int t = 0; t < 4; ++t)
    #pragma unroll
    for (int r = 0; r < 4; ++r)
      qp_s[(lq * 4 + r) * 72 + t * 16 + lrow] = f2bf(sc[t][r] * sr[r]);

  // ---- PV: all 56 cols; tiles {0,16,32,40}, 4th overlaps (store lrow>=8)
  short8 ap[2];
  #pragma unroll
  for (int kt = 0; kt < 2; ++kt)
    ap[kt] = *(const short8*)&qp_s[lrow * 72 + kt * 32 + lq * 8];
  #pragma unroll
  for (int ct = 0; ct < 4; ++ct) {
    int c0 = (ct < 3) ? ct * 16 : 40;
    int col = c0 + lrow;
    f32x4 ov = {0.f, 0.f, 0.f, 0.f};
    #pragma unroll
    for (int kt = 0; kt < 2; ++kt) {
      short8 bv = *(const short8*)&vT_s[col * 72 + kt * 32 + lq * 8];
      ov = __builtin_amdgcn_mfma_f32_16x16x32_bf16(ap[kt], bv, ov, 0, 0, 0);
    }
    if (ct < 3 || lrow >= 8) {
      #pragma unroll
      for (int r = 0; r < 4; ++r) {
        int row = lq * 4 + r;
        size_t token = ((size_t)(b * 64 + nh * 4 + (row >> 2))) * 64 + (nw * 4 + (row & 3));
        o_bf[token * 224 + h * 56 + col] = f2bf(ov[r]);
      }
    }
  }
}

// ---------------------------- attn_proj GEMM + bias + residual into hs2
__global__ __launch_bounds__(256, 5) void aproj_kernel(
    const short* __restrict__ o_bf, const short* __restrict__ apF,
    const float* __restrict__ apb, float* __restrict__ hs2) {
  __shared__ alignas(16) short o_s[64 * 232];
  int blk = blockIdx.x;  // 512 x 64 tokens
  int tid = threadIdx.x;
  for (int e = tid; e < 64 * 28; e += 256) {
    int m = e / 28, c = e % 28;
    *(short8*)&o_s[m * 232 + c * 8] =
        *(const short8*)(o_bf + ((size_t)blk * 64 + m) * 224 + c * 8);
  }
  __syncthreads();
  int wave = tid >> 6, lane = tid & 63, lrow = lane & 15, lq = lane >> 4;
  short8 Ao[7];
  #pragma unroll
  for (int kt = 0; kt < 7; ++kt)
    Ao[kt] = *(const short8*)&o_s[(wave * 16 + lrow) * 232 + kt * 32 + lq * 8];
  for (int pr = 0; pr < 7; ++pr) {
    int c0 = pr * 32 + lrow, c1 = c0 + 16;
    f32x4 acc0 = {0.f, 0.f, 0.f, 0.f}, acc1 = {0.f, 0.f, 0.f, 0.f};
    #pragma unroll
    for (int kt = 0; kt < 7; ++kt) {
      short8 b0 = *(const short8*)(apF + (((2 * pr) * 7 + kt) * 64 + lane) * 8);
      short8 b1 = *(const short8*)(apF + (((2 * pr + 1) * 7 + kt) * 64 + lane) * 8);
      acc0 = __builtin_amdgcn_mfma_f32_16x16x32_bf16(Ao[kt], b0, acc0, 0, 0, 0);
      acc1 = __builtin_amdgcn_mfma_f32_16x16x32_bf16(Ao[kt], b1, acc1, 0, 0, 0);
    }
    float bi0 = apb[c0], bi1 = apb[c1];
    #pragma unroll
    for (int r = 0; r < 4; ++r) {
      size_t row = (size_t)blk * 64 + wave * 16 + lq * 4 + r;
      hs2[row * 224 + c0] += acc0[r] + bi0;
      hs2[row * 224 + c1] += acc1[r] + bi1;
    }
  }
}

// ------------- fused LN2 + mlp1 + GELU + mlp2 + residual, 32x32x16 MFMA
// R12: split-k hidden. hid_s holds 448 channels at a time ([32][456]);
// GEMM2 accumulates across the two phases in one f32x16.
template <int NT>
__device__ __forceinline__ void mlp1_tiles(
    int nt0, int tbase, const short* ln_s, const short* __restrict__ m1F,
    const float* __restrict__ b1, short* hid_s, int nl, int half, int lane) {
  f32x16 acc[NT];
  #pragma unroll
  for (int i = 0; i < NT; ++i)
    #pragma unroll
    for (int r = 0; r < 16; ++r) acc[i][r] = 0.f;
  #pragma unroll
  for (int kt = 0; kt < 14; ++kt) {
    short8 a = *(const short8*)&ln_s[nl * 232 + kt * 16 + half * 8];
    #pragma unroll
    for (int i = 0; i < NT; ++i) {
      short8 bw = *(const short8*)(m1F + ((size_t)((nt0 + i) * 14 + kt) * 64 + lane) * 8);
      acc[i] = __builtin_amdgcn_mfma_f32_32x32x16_bf16(a, bw, acc[i], 0, 0, 0);
    }
  }
  #pragma unroll
  for (int i = 0; i < NT; ++i) {
    int col = (nt0 + i) * 32 + nl;                 // global hidden channel
    int lcol = (nt0 + i - tbase) * 32 + nl;        // local col in hid_s
    float bi = b1[col];
    #pragma unroll
    for (int r = 0; r < 16; ++r) {
      int row = (r & 3) + 8 * (r >> 2) + 4 * half;
      hid_s[row * 456 + lcol] = f2bf(gelu_fast(acc[i][r] + bi));
    }
  }
}

__global__ __launch_bounds__(512, 6) void mlp_kernel(
    const float* __restrict__ hs2, const float* __restrict__ g2,
    const float* __restrict__ b2, const short* __restrict__ m1F,
    const float* __restrict__ b1, const short* __restrict__ m2F,
    const float* __restrict__ b2b, float* __restrict__ out) {
  __shared__ alignas(16) short ln_s[32 * 232];   // 14,848 B
  __shared__ alignas(16) short hid_s[32 * 456];  // 29,184 B => 44,032 B
  int blk = blockIdx.x;  // 1024 x 32 tokens
  int tid = threadIdx.x;
  size_t base = (size_t)blk * 32 * 224;
  {
    int row = tid >> 4, l = tid & 15;
    const float* rp = hs2 + base + (size_t)row * 224;
    float v[14];
    float s = 0.f;
    #pragma unroll
    for (int c = 0; c < 14; ++c) { v[c] = rp[l + 16 * c]; s += v[c]; }
    #pragma unroll
    for (int off = 8; off; off >>= 1) s += __shfl_xor(s, off, 16);
    float mean = s * (1.f / 224.f);
    float s2 = 0.f;
    #pragma unroll
    for (int c = 0; c < 14; ++c) { float d = v[c] - mean; s2 = fmaf(d, d, s2); }
    #pragma unroll
    for (int off = 8; off; off >>= 1) s2 += __shfl_xor(s2, off, 16);
    float rs = rsqrtf(s2 * (1.f / 224.f) + 1e-6f);
    #pragma unroll
    for (int c = 0; c < 14; ++c) {
      int cc = l + 16 * c;
      ln_s[row * 232 + cc] = f2bf((v[c] - mean) * rs * g2[cc] + b2[cc]);
    }
  }
  __syncthreads();
  int wave = tid >> 6, lane = tid & 63;
  int nl = lane & 31, half = lane >> 5;
  int nt2 = wave;  // GEMM2 output col tile (wave < 7)
  f32x16 acg = {0.f,0.f,0.f,0.f,0.f,0.f,0.f,0.f,0.f,0.f,0.f,0.f,0.f,0.f,0.f,0.f};
  f32x4 res[4];

  #pragma unroll
  for (int ph = 0; ph < 2; ++ph) {
    int tbase = ph * 14;
    // GEMM1 phase: hidden tiles tbase..tbase+13 -> hid_s (448 channels)
    if (wave < 6)
      mlp1_tiles<2>(tbase + wave * 2, tbase, ln_s, m1F, b1, hid_s, nl, half, lane);
    else
      mlp1_tiles<1>(tbase + 12 + (wave - 6), tbase, ln_s, m1F, b1, hid_s, nl, half, lane);
    __syncthreads();  // hid ready
    if (ph == 1 && wave < 7) {
      // prefetch residual: hides under the second 28-MFMA k-loop
      #pragma unroll
      for (int r = 0; r < 4; ++r) {
        int row = (r & 3) + 8 * (r >> 2) + 4 * half;  // rows 0..15 pattern? no:
        // residual rows span all 16 outputs of acg -> rows (q&3)+8*(q>>2)+4*half
        res[r][0] = 0.f;  // placeholder, replaced below
      }
      #pragma unroll
      for (int rq = 0; rq < 4; ++rq) {
        // acg regs rq*4..rq*4+3 -> rows (r&3)+8*(r>>2)+4*half for r in quad
        // load individually (scalar, 16 loads) — same as R9 epilogue
      }
    }
    if (wave < 7) {
      #pragma unroll 4
      for (int kt = 0; kt < 28; ++kt) {
        short8 a = *(const short8*)&hid_s[nl * 456 + kt * 16 + half * 8];
        short8 bw = *(const short8*)(m2F + ((size_t)(nt2 * 56 + ph * 28 + kt) * 64 + lane) * 8);
        acg = __builtin_amdgcn_mfma_f32_32x32x16_bf16(a, bw, acg, 0, 0, 0);
      }
    }
    if (ph == 0) __syncthreads();  // all P1 reads done before overwrite
  }
  if (wave < 7) {
    int col = nt2 * 32 + nl;
    float bi = b2b[col];
    #pragma unroll
    for (int r = 0; r < 16; ++r) {
      int row = (r & 3) + 8 * (r >> 2) + 4 * half;
      size_t idx = base + (size_t)row * 224 + col;
      out[idx] = hs2[idx] + acg[r] + bi;
    }
  }
}

extern "C" void kernel_launch(void* const* d_in, const int* in_sizes, int n_in,
                              void* d_out, int out_size, void* d_ws, size_t ws_size,
                              hipStream_t stream) {
  const float* x    = (const float*)d_in[0];
  const float* ln1g = (const float*)d_in[1];
  const float* ln1b = (const float*)d_in[2];
  const float* qkvw = (const float*)d_in[3];
  const float* qkvb = (const float*)d_in[4];
  const float* apw  = (const float*)d_in[5];
  const float* apb  = (const float*)d_in[6];
  const float* rpw  = (const float*)d_in[7];
  const float* rpb  = (const float*)d_in[8];
  const float* ln2g = (const float*)d_in[9];
  const float* ln2b = (const float*)d_in[10];
  const float* w1   = (const float*)d_in[11];
  const float* b1   = (const float*)d_in[12];
  const float* w2   = (const float*)d_in[13];
  const float* b2   = (const float*)d_in[14];
  float* out = (float*)d_out;

  short* hs_bf = (short*)d_ws;
  float* hs2   = (float*)((char*)d_ws + 29360128);
  short* o_bf  = (short*)((char*)d_ws + 58720256);
  short* wF    = (short*)((char*)d_ws + 73400320);

  cast_w_kernel<<<1024, 256, 0, stream>>>(qkvw, rpw, apw, w1, w2, wF);
  ln1_kernel<<<16384, 256, 0, stream>>>(x, ln1g, ln1b, hs_bf);
  respool_kernel<<<2048, 256, 0, stream>>>(hs_bf, wF + 90112, rpb, hs2);
  attn_kernel<<<2048, 256, 0, stream>>>(hs_bf, wF, qkvb, o_bf);
  aproj_kernel<<<512, 256, 0, stream>>>(o_bf, wF + 118784, apb, hs2);
  mlp_kernel<<<1024, 512, 0, stream>>>(hs2, ln2g, ln2b, wF + 168960, b1,
                                       wF + 369664, b2, out);
}

// Round 6
// 252.100 us; speedup vs baseline: 1.0928x; 1.0928x over previous
//
#include <hip/hip_runtime.h>
#include <hip/hip_bf16.h>
#include <math.h>

// SAM2 MultiScale Block — round 13:
//  - REVERT mlp to R11 (split-k R12 regressed: FETCH +11MB, single dependent
//    GEMM2 MFMA chain, 2 extra lockstep barriers; occupancy wasn't binding).
//  - FUSE aproj into attn: PV output -> own qp_s region (P dead after ap
//    loads; same-wave DS in-order), 1 barrier, waves split 14 N-tiles
//    {4,4,3,3}, RMW into hs2. Kills o_bf roundtrip (29MB) + launch.
// ln1/respool/cast identical to R11.
// DIM=112(K pad 128), DIM_OUT=224, HEADS=4, HD=56, WS=8, QS=2, MLP=896
//
// ws layout (bytes):
//   hs_bf @ 0          : 131072x112 bf16 = 29,360,128
//   hs2   @ 29,360,128 : 32768x224 f32   = 29,360,128
//   o_bf  @ 58,720,256 : (unused since R13)
//   wF    @ 73,400,320 : frag-packed bf16 weights (elems):
//     qkvF 704x128 @ +0       rpF 224x128 @ +90112   apF 224x224 @ +118784
//     m1F  896x224 @ +168960  m2F 224x896 @ +369664  (end 570368)
// 16x16 frag order (qkvF/rpF/apF): (n,k) -> tile=(n/16)*KT+(k/32);
//   flat=(tile*64+lane)*8+j, lane=((k%32)/8)*16+(n%16), j=k%8.
// 32x32 frag order (m1F/m2F): (n,k) -> tile=(n/32)*KT16+(k/16);
//   flat=(tile*64+lane)*8+j, lane=((k%16)/8)*32+(n%32), j=k%8.

#define SCALE_A 0.13363062095621219f  // 56^-0.5

typedef __attribute__((ext_vector_type(8))) short short8;
typedef __attribute__((ext_vector_type(4))) short short4v;
typedef __attribute__((ext_vector_type(4))) float f32x4;
typedef __attribute__((ext_vector_type(16))) float f32x16;

__device__ inline short f2bf(float x) {
  union { float f; unsigned u; } v; v.f = x;
  unsigned r = v.u + 0x7fff + ((v.u >> 16) & 1);
  return (short)(r >> 16);
}
// sigmoid-form tanh-GELU: x * sigmoid(1.59576912*(x + 0.044715 x^3)).
__device__ inline float gelu_fast(float x) {
  float x2 = x * x;
  float p = fmaf(x2, 0.044715f, 1.0f);
  float t = -1.5957691216057308f * x * p;
  return x / (1.0f + __expf(t));
}

// ------------------------------------------- weight cast to frag order
__global__ void cast_w_kernel(const float* __restrict__ qkv_w,
                              const float* __restrict__ rp_w,
                              const float* __restrict__ ap_w,
                              const float* __restrict__ m1_w,
                              const float* __restrict__ m2_w,
                              short* __restrict__ wF) {
  int tid = blockIdx.x * blockDim.x + threadIdx.x;
  int stride = gridDim.x * blockDim.x;
  // qkvF: permuted cols cp = h*176 + cl; cl: [q 0..55|k 56..111|v 112..167|pad]
  for (int e = tid; e < 90112; e += stride) {
    int j = e & 7, lr = (e >> 3) & 15, lqq = (e >> 7) & 3, tile = e >> 9;
    int kt = tile & 3, nt = tile >> 2;
    int cp = nt * 16 + lr;
    int h = cp / 176, cl = cp % 176;
    int k = kt * 32 + lqq * 8 + j;
    float val = 0.f;
    if (k < 112 && cl < 168) {
      int bcol = (cl < 56) ? (h * 56 + cl)
               : (cl < 112) ? (224 + h * 56 + (cl - 56))
                            : (448 + h * 56 + (cl - 112));
      val = qkv_w[k * 672 + bcol];
    }
    wF[e] = f2bf(val);
  }
  for (int e = tid; e < 28672; e += stride) {  // rpF: N=224, KT=4 (16x16)
    int j = e & 7, lr = (e >> 3) & 15, lqq = (e >> 7) & 3, tile = e >> 9;
    int kt = tile & 3, nt = tile >> 2;
    int n = nt * 16 + lr, k = kt * 32 + lqq * 8 + j;
    wF[90112 + e] = (k < 112) ? f2bf(rp_w[k * 224 + n]) : (short)0;
  }
  for (int e = tid; e < 50176; e += stride) {  // apF: N=224, KT=7 (16x16)
    int j = e & 7, lr = (e >> 3) & 15, lqq = (e >> 7) & 3, tile = e >> 9;
    int kt = tile % 7, nt = tile / 7;
    int n = nt * 16 + lr, k = kt * 32 + lqq * 8 + j;
    wF[118784 + e] = f2bf(ap_w[k * 224 + n]);
  }
  for (int e = tid; e < 200704; e += stride) {  // m1F: N=896/32, K=224/16 (32x32)
    int j = e & 7, lane = (e >> 3) & 63, unit = e >> 9;
    int kt = unit % 14, nt = unit / 14;
    int n = nt * 32 + (lane & 31), k = kt * 16 + (lane >> 5) * 8 + j;
    wF[168960 + e] = f2bf(m1_w[k * 896 + n]);
  }
  for (int e = tid; e < 200704; e += stride) {  // m2F: N=224/32, K=896/16 (32x32)
    int j = e & 7, lane = (e >> 3) & 63, unit = e >> 9;
    int kt = unit % 56, nt = unit / 56;
    int n = nt * 32 + (lane & 31), k = kt * 16 + (lane >> 5) * 8 + j;
    wF[369664 + e] = f2bf(m2_w[k * 224 + n]);
  }
}

// ---------------------------------------------------------------- LN1 -> bf16
// R11: 2 rows/wave, f32x4 loads (lanes 0..27 of each 32-half), shfl_xor(32)
// reduce, short4 bf16 stores. 8 rows/block, 16384 blocks.
__global__ __launch_bounds__(256) void ln1_kernel(
    const float* __restrict__ x, const float* __restrict__ g,
    const float* __restrict__ b, short* __restrict__ hs) {
  int wave = threadIdx.x >> 6, lane = threadIdx.x & 63;
  int half = lane >> 5, sub = lane & 31;
  size_t row = (size_t)blockIdx.x * 8 + wave * 2 + half;
  const float* rp = x + row * 112;
  f32x4 v = {0.f, 0.f, 0.f, 0.f};
  if (sub < 28) v = *(const f32x4*)(rp + sub * 4);
  float s = v[0] + v[1] + v[2] + v[3];
  #pragma unroll
  for (int off = 16; off; off >>= 1) s += __shfl_xor(s, off, 32);
  float mean = s * (1.f / 112.f);
  float s2 = 0.f;
  #pragma unroll
  for (int q = 0; q < 4; ++q) { float d = v[q] - mean; s2 = fmaf(d, d, s2); }
  if (sub >= 28) s2 = 0.f;
  #pragma unroll
  for (int off = 16; off; off >>= 1) s2 += __shfl_xor(s2, off, 32);
  float rs = rsqrtf(s2 * (1.f / 112.f) + 1e-6f);
  if (sub < 28) {
    f32x4 gg = *(const f32x4*)(g + sub * 4);
    f32x4 bb = *(const f32x4*)(b + sub * 4);
    short4v o;
    #pragma unroll
    for (int q = 0; q < 4; ++q)
      o[q] = f2bf((v[q] - mean) * rs * gg[q] + bb[q]);
    *(short4v*)(hs + row * 112 + sub * 4) = o;
  }
}

// -------------------------------------- res_proj + maxpool2 (MFMA) -> hs2
__global__ __launch_bounds__(256, 8) void respool_kernel(
    const short* __restrict__ hs, const short* __restrict__ rpF,
    const float* __restrict__ bias, float* __restrict__ hs2) {
  __shared__ alignas(16) short w_s[64 * 136];
  int blk = blockIdx.x;  // 2048
  int tid = threadIdx.x;
  for (int e = tid; e < 1024; e += 256) {
    int m = e >> 4, c = e & 15;
    short8* dst = (short8*)&w_s[m * 136 + c * 8];
    if (c < 14) {
      int p = m >> 2, r = m & 3;
      int pix = blk * 16 + p;
      int bb = pix >> 12, ii = (pix >> 6) & 63, jj = pix & 63;
      size_t token = ((size_t)(bb * 128 + 2 * ii + (r >> 1))) * 128 + 2 * jj + (r & 1);
      *dst = *(const short8*)(hs + token * 112 + c * 8);
    } else {
      short8 z = {0, 0, 0, 0, 0, 0, 0, 0};
      *dst = z;
    }
  }
  __syncthreads();
  int wave = tid >> 6, lane = tid & 63, lrow = lane & 15, lq = lane >> 4;
  short8 Ar[4];
  #pragma unroll
  for (int kt = 0; kt < 4; ++kt)
    Ar[kt] = *(const short8*)&w_s[(wave * 16 + lrow) * 136 + kt * 32 + lq * 8];
  int p = wave * 4 + lq;
  for (int pr = 0; pr < 7; ++pr) {
    int c0 = pr * 32 + lrow, c1 = c0 + 16;
    f32x4 acc0 = {0.f, 0.f, 0.f, 0.f}, acc1 = {0.f, 0.f, 0.f, 0.f};
    #pragma unroll
    for (int kt = 0; kt < 4; ++kt) {
      short8 b0 = *(const short8*)(rpF + (((2 * pr) * 4 + kt) * 64 + lane) * 8);
      short8 b1 = *(const short8*)(rpF + (((2 * pr + 1) * 4 + kt) * 64 + lane) * 8);
      acc0 = __builtin_amdgcn_mfma_f32_16x16x32_bf16(Ar[kt], b0, acc0, 0, 0, 0);
      acc1 = __builtin_amdgcn_mfma_f32_16x16x32_bf16(Ar[kt], b1, acc1, 0, 0, 0);
    }
    float m0 = fmaxf(fmaxf(acc0[0], acc0[1]), fmaxf(acc0[2], acc0[3])) + bias[c0];
    float m1 = fmaxf(fmaxf(acc1[0], acc1[1]), fmaxf(acc1[2], acc1[3])) + bias[c1];
    hs2[(size_t)(blk * 16 + p) * 224 + c0] = m0;
    hs2[(size_t)(blk * 16 + p) * 224 + c1] = m1;
  }
}

// ------------------- fused windowed attention + attn_proj, round 13
// head-per-wave (R9) + fused aproj: PV output -> own qp region (bf16),
// barrier, waves split 14 N-tiles {4,4,3,3}, 7 MFMA each, RMW into hs2.
__global__ __launch_bounds__(256, 2) void attn_kernel(
    const short* __restrict__ hs, const short* __restrict__ qkvF,
    const float* __restrict__ qkv_b, const short* __restrict__ apF,
    const float* __restrict__ apb, float* __restrict__ hs2) {
  __shared__ alignas(16) short u_s[4 * 9792];   // 78,336 B
  int win = blockIdx.x;                         // 2048
  int nw = win & 15, nh = (win >> 4) & 15, b = win >> 8;
  int tid = threadIdx.x;
  int wave = tid >> 6, lane = tid & 63, lrow = lane & 15, lq = lane >> 4;
  short* w_s  = u_s;                    // [64*136] staging (union, hoist only)
  short* k_s  = u_s + wave * 9792;      // private
  short* vT_s = k_s + 4608;
  short* qp_s = k_s + 8640;             // q -> P -> o(head) region

  for (int e = tid; e < 1024; e += 256) {
    int m = e >> 4, c = e & 15;
    short8* dst = (short8*)&w_s[m * 136 + c * 8];
    if (c < 14) {
      int p = m >> 2, r = m & 3;
      int tr = (p >> 2) * 2 + (r >> 1), tc = (p & 3) * 2 + (r & 1);
      size_t token = ((size_t)(b * 128 + nh * 8 + tr)) * 128 + (nw * 8 + tc);
      *dst = *(const short8*)(hs + token * 112 + c * 8);
    } else {
      short8 z = {0, 0, 0, 0, 0, 0, 0, 0};
      *dst = z;
    }
  }
  __syncthreads();  // staging done

  // hoist A-frags for all 4 M-tiles: 64 VGPR
  short8 Aw[4][4];
  #pragma unroll
  for (int mt = 0; mt < 4; ++mt)
    #pragma unroll
    for (int kt = 0; kt < 4; ++kt)
      Aw[mt][kt] = *(const short8*)&w_s[(mt * 16 + lrow) * 136 + kt * 32 + lq * 8];
  __syncthreads();  // hoists done; per-wave regions may be written

  // zero pads (per-wave, one short8 store per lane)
  {
    short8 z = {0, 0, 0, 0, 0, 0, 0, 0};
    *(short8*)&k_s[lane * 72 + 56] = z;          // k pad cols 56..63, 64 rows
    if (lane < 16) *(short8*)&qp_s[lane * 72 + 56] = z;  // q pad
  }

  int h = wave;  // head ownership

  // ---- qkv: 11 N-tiles for this head, all 4 M-tiles
  #pragma unroll 2
  for (int t = 0; t < 11; ++t) {
    int cl = t * 16 + lrow;
    f32x4 ac[4] = {{0.f,0.f,0.f,0.f},{0.f,0.f,0.f,0.f},
                   {0.f,0.f,0.f,0.f},{0.f,0.f,0.f,0.f}};
    short8 bw[4];
    #pragma unroll
    for (int kt = 0; kt < 4; ++kt)
      bw[kt] = *(const short8*)(qkvF + (((h * 11 + t) * 4 + kt) * 64 + lane) * 8);
    #pragma unroll
    for (int kt = 0; kt < 4; ++kt)
      #pragma unroll
      for (int mt = 0; mt < 4; ++mt)
        ac[mt] = __builtin_amdgcn_mfma_f32_16x16x32_bf16(Aw[mt][kt], bw[kt], ac[mt], 0, 0, 0);
    if (cl < 56) {
      float bias = qkv_b[h * 56 + cl];
      #pragma unroll
      for (int mt = 0; mt < 4; ++mt) {
        float mx = fmaxf(fmaxf(ac[mt][0], ac[mt][1]),
                         fmaxf(ac[mt][2], ac[mt][3])) + bias;
        qp_s[(mt * 4 + lq) * 72 + cl] = f2bf(mx * SCALE_A);
      }
    } else if (cl < 112) {
      float bias = qkv_b[224 + h * 56 + (cl - 56)];
      #pragma unroll
      for (int mt = 0; mt < 4; ++mt)
        #pragma unroll
        for (int r = 0; r < 4; ++r)
          k_s[(mt * 16 + lq * 4 + r) * 72 + (cl - 56)] = f2bf(ac[mt][r] + bias);
    } else if (cl < 168) {
      float bias = qkv_b[448 + h * 56 + (cl - 112)];
      #pragma unroll
      for (int mt = 0; mt < 4; ++mt) {
        short4v pk = {f2bf(ac[mt][0] + bias), f2bf(ac[mt][1] + bias),
                      f2bf(ac[mt][2] + bias), f2bf(ac[mt][3] + bias)};
        *(short4v*)&vT_s[(cl - 112) * 72 + mt * 16 + lq * 4] = pk;
      }
    }
  }
  // no barrier: same-wave LDS write->read (waitcnt handles it)

  // ---- scores: 16 queries x 64 keys
  short8 aq[2];
  #pragma unroll
  for (int kt = 0; kt < 2; ++kt)
    aq[kt] = *(const short8*)&qp_s[lrow * 72 + kt * 32 + lq * 8];
  f32x4 sc[4];
  #pragma unroll
  for (int t = 0; t < 4; ++t) {
    sc[t][0] = sc[t][1] = sc[t][2] = sc[t][3] = 0.f;
    #pragma unroll
    for (int kt = 0; kt < 2; ++kt) {
      short8 bk = *(const short8*)&k_s[(t * 16 + lrow) * 72 + kt * 32 + lq * 8];
      sc[t] = __builtin_amdgcn_mfma_f32_16x16x32_bf16(aq[kt], bk, sc[t], 0, 0, 0);
    }
  }
  // ---- softmax rows lq*4+r: reduce over t (local) and lrow (16-lane shfl)
  float mr[4], sr[4];
  #pragma unroll
  for (int r = 0; r < 4; ++r)
    mr[r] = fmaxf(fmaxf(sc[0][r], sc[1][r]), fmaxf(sc[2][r], sc[3][r]));
  #pragma unroll
  for (int off = 8; off; off >>= 1)
    #pragma unroll
    for (int r = 0; r < 4; ++r) mr[r] = fmaxf(mr[r], __shfl_xor(mr[r], off, 16));
  #pragma unroll
  for (int r = 0; r < 4; ++r) {
    #pragma unroll
    for (int t = 0; t < 4; ++t) sc[t][r] = __expf(sc[t][r] - mr[r]);
    sr[r] = sc[0][r] + sc[1][r] + sc[2][r] + sc[3][r];
  }
  #pragma unroll
  for (int off = 8; off; off >>= 1)
    #pragma unroll
    for (int r = 0; r < 4; ++r) sr[r] += __shfl_xor(sr[r], off, 16);
  #pragma unroll
  for (int r = 0; r < 4; ++r) sr[r] = 1.f / sr[r];
  // normalized P -> qp_s (q is dead; same-wave write->read, no barrier)
  #pragma unroll
  for (int t = 0; t < 4; ++t)
    #pragma unroll
    for (int r = 0; r < 4; ++r)
      qp_s[(lq * 4 + r) * 72 + t * 16 + lrow] = f2bf(sc[t][r] * sr[r]);

  // ---- PV: all 56 cols; tiles {0,16,32,40}, 4th overlaps (store lrow>=8).
  // P fully consumed into ap[2] registers -> qp_s becomes this head's o.
  short8 ap[2];
  #pragma unroll
  for (int kt = 0; kt < 2; ++kt)
    ap[kt] = *(const short8*)&qp_s[lrow * 72 + kt * 32 + lq * 8];
  #pragma unroll
  for (int ct = 0; ct < 4; ++ct) {
    int c0 = (ct < 3) ? ct * 16 : 40;
    int col = c0 + lrow;
    f32x4 ov = {0.f, 0.f, 0.f, 0.f};
    #pragma unroll
    for (int kt = 0; kt < 2; ++kt) {
      short8 bv = *(const short8*)&vT_s[col * 72 + kt * 32 + lq * 8];
      ov = __builtin_amdgcn_mfma_f32_16x16x32_bf16(ap[kt], bv, ov, 0, 0, 0);
    }
    if (ct < 3 || lrow >= 8) {
      #pragma unroll
      for (int r = 0; r < 4; ++r)
        qp_s[(lq * 4 + r) * 72 + col] = f2bf(ov[r]);  // o (head h), same-wave
    }
  }
  __syncthreads();  // all heads' o ready in qp regions

  // ---- fused attn_proj: A = o rows 0..15 (K=224 spread over head regions)
  short8 Ao[7];
  #pragma unroll
  for (int kt = 0; kt < 7; ++kt) {
    int c = kt * 32 + lq * 8;               // o channel 0..216
    int h2 = (c >= 168) ? 3 : (c >= 112) ? 2 : (c >= 56) ? 1 : 0;
    Ao[kt] = *(const short8*)&u_s[h2 * 9792 + 8640 + lrow * 72 + (c - h2 * 56)];
  }
  int nt0 = (wave < 2) ? wave * 4 : 8 + (wave - 2) * 3;
  int ncnt2 = (wave < 2) ? 4 : 3;
  for (int i = 0; i < ncnt2; ++i) {
    int nt = nt0 + i;
    f32x4 acc = {0.f, 0.f, 0.f, 0.f};
    #pragma unroll
    for (int kt = 0; kt < 7; ++kt) {
      short8 bw = *(const short8*)(apF + ((nt * 7 + kt) * 64 + lane) * 8);
      acc = __builtin_amdgcn_mfma_f32_16x16x32_bf16(Ao[kt], bw, acc, 0, 0, 0);
    }
    int col2 = nt * 16 + lrow;
    float bi = apb[col2];
    #pragma unroll
    for (int r = 0; r < 4; ++r) {
      size_t token = ((size_t)(b * 64 + nh * 4 + lq)) * 64 + nw * 4 + r;
      float* p = &hs2[token * 224 + col2];
      *p += acc[r] + bi;
    }
  }
}

// ------------- fused LN2 + mlp1 + GELU + mlp2 + residual, 32x32x16 MFMA
// (R11/R9 version: lane=channel epilogues, fused multi-tile GEMM1, res
// prefetch, dual GEMM2 accumulators)
template <int NT>
__device__ __forceinline__ void mlp1_tiles(
    int nt0, const short* ln_s, const short* __restrict__ m1F,
    const float* __restrict__ b1, short* hid_s, int nl, int half, int lane) {
  f32x16 acc[NT];
  #pragma unroll
  for (int i = 0; i < NT; ++i)
    #pragma unroll
    for (int r = 0; r < 16; ++r) acc[i][r] = 0.f;
  #pragma unroll
  for (int kt = 0; kt < 14; ++kt) {
    short8 a = *(const short8*)&ln_s[nl * 232 + kt * 16 + half * 8];
    #pragma unroll
    for (int i = 0; i < NT; ++i) {
      short8 bw = *(const short8*)(m1F + ((size_t)((nt0 + i) * 14 + kt) * 64 + lane) * 8);
      acc[i] = __builtin_amdgcn_mfma_f32_32x32x16_bf16(a, bw, acc[i], 0, 0, 0);
    }
  }
  #pragma unroll
  for (int i = 0; i < NT; ++i) {
    int col = (nt0 + i) * 32 + nl;
    float bi = b1[col];
    #pragma unroll
    for (int r = 0; r < 16; ++r) {
      int row = (r & 3) + 8 * (r >> 2) + 4 * half;
      hid_s[row * 904 + col] = f2bf(gelu_fast(acc[i][r] + bi));
    }
  }
}

__global__ __launch_bounds__(512, 4) void mlp_kernel(
    const float* __restrict__ hs2, const float* __restrict__ g2,
    const float* __restrict__ b2, const short* __restrict__ m1F,
    const float* __restrict__ b1, const short* __restrict__ m2F,
    const float* __restrict__ b2b, float* __restrict__ out) {
  __shared__ alignas(16) short ln_s[32 * 232];   // 14,848 B
  __shared__ alignas(16) short hid_s[32 * 904];  // 57,856 B => 72,704 B
  int blk = blockIdx.x;  // 1024 x 32 tokens
  int tid = threadIdx.x;
  size_t base = (size_t)blk * 32 * 224;
  {
    int row = tid >> 4, l = tid & 15;
    const float* rp = hs2 + base + (size_t)row * 224;
    float v[14];
    float s = 0.f;
    #pragma unroll
    for (int c = 0; c < 14; ++c) { v[c] = rp[l + 16 * c]; s += v[c]; }
    #pragma unroll
    for (int off = 8; off; off >>= 1) s += __shfl_xor(s, off, 16);
    float mean = s * (1.f / 224.f);
    float s2 = 0.f;
    #pragma unroll
    for (int c = 0; c < 14; ++c) { float d = v[c] - mean; s2 = fmaf(d, d, s2); }
    #pragma unroll
    for (int off = 8; off; off >>= 1) s2 += __shfl_xor(s2, off, 16);
    float rs = rsqrtf(s2 * (1.f / 224.f) + 1e-6f);
    #pragma unroll
    for (int c = 0; c < 14; ++c) {
      int cc = l + 16 * c;
      ln_s[row * 232 + cc] = f2bf((v[c] - mean) * rs * g2[cc] + b2[cc]);
    }
  }
  __syncthreads();
  int wave = tid >> 6, lane = tid & 63;
  int nl = lane & 31, half = lane >> 5;
  if (wave < 4) mlp1_tiles<4>(wave * 4, ln_s, m1F, b1, hid_s, nl, half, lane);
  else          mlp1_tiles<3>(16 + (wave - 4) * 3, ln_s, m1F, b1, hid_s, nl, half, lane);
  __syncthreads();
  if (wave < 7) {
    int nt = wave;
    int col = nt * 32 + nl;
    float res[16];
    #pragma unroll
    for (int r = 0; r < 16; ++r) {
      int row = (r & 3) + 8 * (r >> 2) + 4 * half;
      res[r] = hs2[base + (size_t)row * 224 + col];
    }
    f32x16 ac0 = {0.f,0.f,0.f,0.f,0.f,0.f,0.f,0.f,0.f,0.f,0.f,0.f,0.f,0.f,0.f,0.f};
    f32x16 ac1 = {0.f,0.f,0.f,0.f,0.f,0.f,0.f,0.f,0.f,0.f,0.f,0.f,0.f,0.f,0.f,0.f};
    #pragma unroll 4
    for (int kt = 0; kt < 56; kt += 2) {
      short8 a0 = *(const short8*)&hid_s[nl * 904 + kt * 16 + half * 8];
      short8 a1 = *(const short8*)&hid_s[nl * 904 + (kt + 1) * 16 + half * 8];
      short8 b0 = *(const short8*)(m2F + ((size_t)(nt * 56 + kt) * 64 + lane) * 8);
      short8 b1 = *(const short8*)(m2F + ((size_t)(nt * 56 + kt + 1) * 64 + lane) * 8);
      ac0 = __builtin_amdgcn_mfma_f32_32x32x16_bf16(a0, b0, ac0, 0, 0, 0);
      ac1 = __builtin_amdgcn_mfma_f32_32x32x16_bf16(a1, b1, ac1, 0, 0, 0);
    }
    float bi = b2b[col];
    #pragma unroll
    for (int r = 0; r < 16; ++r) {
      int row = (r & 3) + 8 * (r >> 2) + 4 * half;
      size_t idx = base + (size_t)row * 224 + col;
      out[idx] = res[r] + ac0[r] + ac1[r] + bi;
    }
  }
}

extern "C" void kernel_launch(void* const* d_in, const int* in_sizes, int n_in,
                              void* d_out, int out_size, void* d_ws, size_t ws_size,
                              hipStream_t stream) {
  const float* x    = (const float*)d_in[0];
  const float* ln1g = (const float*)d_in[1];
  const float* ln1b = (const float*)d_in[2];
  const float* qkvw = (const float*)d_in[3];
  const float* qkvb = (const float*)d_in[4];
  const float* apw  = (const float*)d_in[5];
  const float* apb  = (const float*)d_in[6];
  const float* rpw  = (const float*)d_in[7];
  const float* rpb  = (const float*)d_in[8];
  const float* ln2g = (const float*)d_in[9];
  const float* ln2b = (const float*)d_in[10];
  const float* w1   = (const float*)d_in[11];
  const float* b1   = (const float*)d_in[12];
  const float* w2   = (const float*)d_in[13];
  const float* b2   = (const float*)d_in[14];
  float* out = (float*)d_out;

  short* hs_bf = (short*)d_ws;
  float* hs2   = (float*)((char*)d_ws + 29360128);
  short* wF    = (short*)((char*)d_ws + 73400320);

  cast_w_kernel<<<1024, 256, 0, stream>>>(qkvw, rpw, apw, w1, w2, wF);
  ln1_kernel<<<16384, 256, 0, stream>>>(x, ln1g, ln1b, hs_bf);
  respool_kernel<<<2048, 256, 0, stream>>>(hs_bf, wF + 90112, rpb, hs2);
  attn_kernel<<<2048, 256, 0, stream>>>(hs_bf, wF, qkvb, wF + 118784, apb, hs2);
  mlp_kernel<<<1024, 512, 0, stream>>>(hs2, ln2g, ln2b, wF + 168960, b1,
                                       wF + 369664, b2, out);
}

// Round 7
// 232.764 us; speedup vs baseline: 1.1836x; 1.0831x over previous
//
#include <hip/hip_runtime.h>
#include <hip/hip_bf16.h>
#include <math.h>

// SAM2 MultiScale Block — round 14: fuse respool into attn.
//  - respool kernel DELETED. attn computes res_proj+maxpool with the already-
//    hoisted Aw frags (same 64 staged tokens), after PV, into res_s f32[16][228]
//    placed over wave0's dead k/vT region. Same wave produces+consumes each
//    aproj N-tile's res rows -> same-wave DS order, no extra barrier.
//  - aproj epilogue: hs2 RMW -> pure store (res + acc + apb).
//  - hs_bf now read ONCE (attn); -29MB HBM fetch; -1 launch.
// mlp/ln1/cast identical to R13 (mlp = R11 version).
// DIM=112(K pad 128), DIM_OUT=224, HEADS=4, HD=56, WS=8, QS=2, MLP=896
//
// ws layout (bytes):
//   hs_bf @ 0          : 131072x112 bf16 = 29,360,128
//   hs2   @ 29,360,128 : 32768x224 f32   = 29,360,128
//   wF    @ 73,400,320 : frag-packed bf16 weights (elems):
//     qkvF 704x128 @ +0       rpF 224x128 @ +90112   apF 224x224 @ +118784
//     m1F  896x224 @ +168960  m2F 224x896 @ +369664  (end 570368)
// 16x16 frag order (qkvF/rpF/apF): (n,k) -> tile=(n/16)*KT+(k/32);
//   flat=(tile*64+lane)*8+j, lane=((k%32)/8)*16+(n%16), j=k%8.
// 32x32 frag order (m1F/m2F): (n,k) -> tile=(n/32)*KT16+(k/16);
//   flat=(tile*64+lane)*8+j, lane=((k%16)/8)*32+(n%32), j=k%8.

#define SCALE_A 0.13363062095621219f  // 56^-0.5

typedef __attribute__((ext_vector_type(8))) short short8;
typedef __attribute__((ext_vector_type(4))) short short4v;
typedef __attribute__((ext_vector_type(4))) float f32x4;
typedef __attribute__((ext_vector_type(16))) float f32x16;

__device__ inline short f2bf(float x) {
  union { float f; unsigned u; } v; v.f = x;
  unsigned r = v.u + 0x7fff + ((v.u >> 16) & 1);
  return (short)(r >> 16);
}
// sigmoid-form tanh-GELU: x * sigmoid(1.59576912*(x + 0.044715 x^3)).
__device__ inline float gelu_fast(float x) {
  float x2 = x * x;
  float p = fmaf(x2, 0.044715f, 1.0f);
  float t = -1.5957691216057308f * x * p;
  return x / (1.0f + __expf(t));
}

// ------------------------------------------- weight cast to frag order
__global__ void cast_w_kernel(const float* __restrict__ qkv_w,
                              const float* __restrict__ rp_w,
                              const float* __restrict__ ap_w,
                              const float* __restrict__ m1_w,
                              const float* __restrict__ m2_w,
                              short* __restrict__ wF) {
  int tid = blockIdx.x * blockDim.x + threadIdx.x;
  int stride = gridDim.x * blockDim.x;
  // qkvF: permuted cols cp = h*176 + cl; cl: [q 0..55|k 56..111|v 112..167|pad]
  for (int e = tid; e < 90112; e += stride) {
    int j = e & 7, lr = (e >> 3) & 15, lqq = (e >> 7) & 3, tile = e >> 9;
    int kt = tile & 3, nt = tile >> 2;
    int cp = nt * 16 + lr;
    int h = cp / 176, cl = cp % 176;
    int k = kt * 32 + lqq * 8 + j;
    float val = 0.f;
    if (k < 112 && cl < 168) {
      int bcol = (cl < 56) ? (h * 56 + cl)
               : (cl < 112) ? (224 + h * 56 + (cl - 56))
                            : (448 + h * 56 + (cl - 112));
      val = qkv_w[k * 672 + bcol];
    }
    wF[e] = f2bf(val);
  }
  for (int e = tid; e < 28672; e += stride) {  // rpF: N=224, KT=4 (16x16)
    int j = e & 7, lr = (e >> 3) & 15, lqq = (e >> 7) & 3, tile = e >> 9;
    int kt = tile & 3, nt = tile >> 2;
    int n = nt * 16 + lr, k = kt * 32 + lqq * 8 + j;
    wF[90112 + e] = (k < 112) ? f2bf(rp_w[k * 224 + n]) : (short)0;
  }
  for (int e = tid; e < 50176; e += stride) {  // apF: N=224, KT=7 (16x16)
    int j = e & 7, lr = (e >> 3) & 15, lqq = (e >> 7) & 3, tile = e >> 9;
    int kt = tile % 7, nt = tile / 7;
    int n = nt * 16 + lr, k = kt * 32 + lqq * 8 + j;
    wF[118784 + e] = f2bf(ap_w[k * 224 + n]);
  }
  for (int e = tid; e < 200704; e += stride) {  // m1F: N=896/32, K=224/16 (32x32)
    int j = e & 7, lane = (e >> 3) & 63, unit = e >> 9;
    int kt = unit % 14, nt = unit / 14;
    int n = nt * 32 + (lane & 31), k = kt * 16 + (lane >> 5) * 8 + j;
    wF[168960 + e] = f2bf(m1_w[k * 896 + n]);
  }
  for (int e = tid; e < 200704; e += stride) {  // m2F: N=224/32, K=896/16 (32x32)
    int j = e & 7, lane = (e >> 3) & 63, unit = e >> 9;
    int kt = unit % 56, nt = unit / 56;
    int n = nt * 32 + (lane & 31), k = kt * 16 + (lane >> 5) * 8 + j;
    wF[369664 + e] = f2bf(m2_w[k * 224 + n]);
  }
}

// ---------------------------------------------------------------- LN1 -> bf16
// R11: 2 rows/wave, f32x4 loads (lanes 0..27 of each 32-half), shfl_xor(32)
// reduce, short4 bf16 stores. 8 rows/block, 16384 blocks.
__global__ __launch_bounds__(256) void ln1_kernel(
    const float* __restrict__ x, const float* __restrict__ g,
    const float* __restrict__ b, short* __restrict__ hs) {
  int wave = threadIdx.x >> 6, lane = threadIdx.x & 63;
  int half = lane >> 5, sub = lane & 31;
  size_t row = (size_t)blockIdx.x * 8 + wave * 2 + half;
  const float* rp = x + row * 112;
  f32x4 v = {0.f, 0.f, 0.f, 0.f};
  if (sub < 28) v = *(const f32x4*)(rp + sub * 4);
  float s = v[0] + v[1] + v[2] + v[3];
  #pragma unroll
  for (int off = 16; off; off >>= 1) s += __shfl_xor(s, off, 32);
  float mean = s * (1.f / 112.f);
  float s2 = 0.f;
  #pragma unroll
  for (int q = 0; q < 4; ++q) { float d = v[q] - mean; s2 = fmaf(d, d, s2); }
  if (sub >= 28) s2 = 0.f;
  #pragma unroll
  for (int off = 16; off; off >>= 1) s2 += __shfl_xor(s2, off, 32);
  float rs = rsqrtf(s2 * (1.f / 112.f) + 1e-6f);
  if (sub < 28) {
    f32x4 gg = *(const f32x4*)(g + sub * 4);
    f32x4 bb = *(const f32x4*)(b + sub * 4);
    short4v o;
    #pragma unroll
    for (int q = 0; q < 4; ++q)
      o[q] = f2bf((v[q] - mean) * rs * gg[q] + bb[q]);
    *(short4v*)(hs + row * 112 + sub * 4) = o;
  }
}

// --------- fused windowed attention + attn_proj + res_proj/maxpool, R14
// head-per-wave (R9). After PV: fused respool via still-live Aw frags into
// res_s f32[16][228] (over wave0's dead k/vT region), then aproj with pure
// store of res + acc + apb into hs2.
__global__ __launch_bounds__(256, 2) void attn_kernel(
    const short* __restrict__ hs, const short* __restrict__ qkvF,
    const float* __restrict__ qkv_b, const short* __restrict__ apF,
    const float* __restrict__ apb, const short* __restrict__ rpF,
    const float* __restrict__ rpb, float* __restrict__ hs2) {
  __shared__ alignas(16) short u_s[4 * 9792];   // 78,336 B
  int win = blockIdx.x;                         // 2048
  int nw = win & 15, nh = (win >> 4) & 15, b = win >> 8;
  int tid = threadIdx.x;
  int wave = tid >> 6, lane = tid & 63, lrow = lane & 15, lq = lane >> 4;
  short* w_s  = u_s;                    // [64*136] staging (union, hoist only)
  short* k_s  = u_s + wave * 9792;      // private
  short* vT_s = k_s + 4608;
  short* qp_s = k_s + 8640;             // q -> P -> o(head) region

  for (int e = tid; e < 1024; e += 256) {
    int m = e >> 4, c = e & 15;
    short8* dst = (short8*)&w_s[m * 136 + c * 8];
    if (c < 14) {
      int p = m >> 2, r = m & 3;
      int tr = (p >> 2) * 2 + (r >> 1), tc = (p & 3) * 2 + (r & 1);
      size_t token = ((size_t)(b * 128 + nh * 8 + tr)) * 128 + (nw * 8 + tc);
      *dst = *(const short8*)(hs + token * 112 + c * 8);
    } else {
      short8 z = {0, 0, 0, 0, 0, 0, 0, 0};
      *dst = z;
    }
  }
  __syncthreads();  // staging done

  // hoist A-frags for all 4 M-tiles: 64 VGPR (live through respool!)
  short8 Aw[4][4];
  #pragma unroll
  for (int mt = 0; mt < 4; ++mt)
    #pragma unroll
    for (int kt = 0; kt < 4; ++kt)
      Aw[mt][kt] = *(const short8*)&w_s[(mt * 16 + lrow) * 136 + kt * 32 + lq * 8];
  __syncthreads();  // hoists done; per-wave regions may be written

  // zero pads (per-wave, one short8 store per lane)
  {
    short8 z = {0, 0, 0, 0, 0, 0, 0, 0};
    *(short8*)&k_s[lane * 72 + 56] = z;          // k pad cols 56..63, 64 rows
    if (lane < 16) *(short8*)&qp_s[lane * 72 + 56] = z;  // q pad
  }

  int h = wave;  // head ownership

  // ---- qkv: 11 N-tiles for this head, all 4 M-tiles
  #pragma unroll 2
  for (int t = 0; t < 11; ++t) {
    int cl = t * 16 + lrow;
    f32x4 ac[4] = {{0.f,0.f,0.f,0.f},{0.f,0.f,0.f,0.f},
                   {0.f,0.f,0.f,0.f},{0.f,0.f,0.f,0.f}};
    short8 bw[4];
    #pragma unroll
    for (int kt = 0; kt < 4; ++kt)
      bw[kt] = *(const short8*)(qkvF + (((h * 11 + t) * 4 + kt) * 64 + lane) * 8);
    #pragma unroll
    for (int kt = 0; kt < 4; ++kt)
      #pragma unroll
      for (int mt = 0; mt < 4; ++mt)
        ac[mt] = __builtin_amdgcn_mfma_f32_16x16x32_bf16(Aw[mt][kt], bw[kt], ac[mt], 0, 0, 0);
    if (cl < 56) {
      float bias = qkv_b[h * 56 + cl];
      #pragma unroll
      for (int mt = 0; mt < 4; ++mt) {
        float mx = fmaxf(fmaxf(ac[mt][0], ac[mt][1]),
                         fmaxf(ac[mt][2], ac[mt][3])) + bias;
        qp_s[(mt * 4 + lq) * 72 + cl] = f2bf(mx * SCALE_A);
      }
    } else if (cl < 112) {
      float bias = qkv_b[224 + h * 56 + (cl - 56)];
      #pragma unroll
      for (int mt = 0; mt < 4; ++mt)
        #pragma unroll
        for (int r = 0; r < 4; ++r)
          k_s[(mt * 16 + lq * 4 + r) * 72 + (cl - 56)] = f2bf(ac[mt][r] + bias);
    } else if (cl < 168) {
      float bias = qkv_b[448 + h * 56 + (cl - 112)];
      #pragma unroll
      for (int mt = 0; mt < 4; ++mt) {
        short4v pk = {f2bf(ac[mt][0] + bias), f2bf(ac[mt][1] + bias),
                      f2bf(ac[mt][2] + bias), f2bf(ac[mt][3] + bias)};
        *(short4v*)&vT_s[(cl - 112) * 72 + mt * 16 + lq * 4] = pk;
      }
    }
  }
  // no barrier: same-wave LDS write->read (waitcnt handles it)

  // ---- scores: 16 queries x 64 keys
  short8 aq[2];
  #pragma unroll
  for (int kt = 0; kt < 2; ++kt)
    aq[kt] = *(const short8*)&qp_s[lrow * 72 + kt * 32 + lq * 8];
  f32x4 sc[4];
  #pragma unroll
  for (int t = 0; t < 4; ++t) {
    sc[t][0] = sc[t][1] = sc[t][2] = sc[t][3] = 0.f;
    #pragma unroll
    for (int kt = 0; kt < 2; ++kt) {
      short8 bk = *(const short8*)&k_s[(t * 16 + lrow) * 72 + kt * 32 + lq * 8];
      sc[t] = __builtin_amdgcn_mfma_f32_16x16x32_bf16(aq[kt], bk, sc[t], 0, 0, 0);
    }
  }
  // ---- softmax rows lq*4+r: reduce over t (local) and lrow (16-lane shfl)
  float mr[4], sr[4];
  #pragma unroll
  for (int r = 0; r < 4; ++r)
    mr[r] = fmaxf(fmaxf(sc[0][r], sc[1][r]), fmaxf(sc[2][r], sc[3][r]));
  #pragma unroll
  for (int off = 8; off; off >>= 1)
    #pragma unroll
    for (int r = 0; r < 4; ++r) mr[r] = fmaxf(mr[r], __shfl_xor(mr[r], off, 16));
  #pragma unroll
  for (int r = 0; r < 4; ++r) {
    #pragma unroll
    for (int t = 0; t < 4; ++t) sc[t][r] = __expf(sc[t][r] - mr[r]);
    sr[r] = sc[0][r] + sc[1][r] + sc[2][r] + sc[3][r];
  }
  #pragma unroll
  for (int off = 8; off; off >>= 1)
    #pragma unroll
    for (int r = 0; r < 4; ++r) sr[r] += __shfl_xor(sr[r], off, 16);
  #pragma unroll
  for (int r = 0; r < 4; ++r) sr[r] = 1.f / sr[r];
  // normalized P -> qp_s (q is dead; same-wave write->read, no barrier)
  #pragma unroll
  for (int t = 0; t < 4; ++t)
    #pragma unroll
    for (int r = 0; r < 4; ++r)
      qp_s[(lq * 4 + r) * 72 + t * 16 + lrow] = f2bf(sc[t][r] * sr[r]);

  // ---- PV: all 56 cols; tiles {0,16,32,40}, 4th overlaps (store lrow>=8).
  // P fully consumed into ap[2] registers -> qp_s becomes this head's o.
  short8 ap[2];
  #pragma unroll
  for (int kt = 0; kt < 2; ++kt)
    ap[kt] = *(const short8*)&qp_s[lrow * 72 + kt * 32 + lq * 8];
  #pragma unroll
  for (int ct = 0; ct < 4; ++ct) {
    int c0 = (ct < 3) ? ct * 16 : 40;
    int col = c0 + lrow;
    f32x4 ov = {0.f, 0.f, 0.f, 0.f};
    #pragma unroll
    for (int kt = 0; kt < 2; ++kt) {
      short8 bv = *(const short8*)&vT_s[col * 72 + kt * 32 + lq * 8];
      ov = __builtin_amdgcn_mfma_f32_16x16x32_bf16(ap[kt], bv, ov, 0, 0, 0);
    }
    if (ct < 3 || lrow >= 8) {
      #pragma unroll
      for (int r = 0; r < 4; ++r)
        qp_s[(lq * 4 + r) * 72 + col] = f2bf(ov[r]);  // o (head h), same-wave
    }
  }
  __syncthreads();  // all heads' o ready; all k/vT regions now DEAD

  // ---- fused respool: this wave's aproj N-tiles, all 4 M-tiles via Aw.
  // res_s over wave0's dead k/vT region: f32[16][228] = 14,592 B < 17,280 B.
  // D[m=lq*4+r][n=nt*16+lrow] of M-tile mt -> quad r of pixel (row nh*4+mt,
  // col nw*4+lq) -> res row p = mt*4+lq. Same wave later reads rows lq*4+r
  // at the same cols -> same-wave DS order, no barrier.
  float* res_s = (float*)u_s;
  int nt0 = (wave < 2) ? wave * 4 : 8 + (wave - 2) * 3;
  int ncnt2 = (wave < 2) ? 4 : 3;
  for (int i = 0; i < ncnt2; ++i) {
    int nt = nt0 + i;
    f32x4 racc[4] = {{0.f,0.f,0.f,0.f},{0.f,0.f,0.f,0.f},
                     {0.f,0.f,0.f,0.f},{0.f,0.f,0.f,0.f}};
    short8 rw[4];
    #pragma unroll
    for (int kt = 0; kt < 4; ++kt)
      rw[kt] = *(const short8*)(rpF + (((nt * 4) + kt) * 64 + lane) * 8);
    #pragma unroll
    for (int kt = 0; kt < 4; ++kt)
      #pragma unroll
      for (int mt = 0; mt < 4; ++mt)
        racc[mt] = __builtin_amdgcn_mfma_f32_16x16x32_bf16(Aw[mt][kt], rw[kt], racc[mt], 0, 0, 0);
    float bi = rpb[nt * 16 + lrow];
    #pragma unroll
    for (int mt = 0; mt < 4; ++mt) {
      float mx = fmaxf(fmaxf(racc[mt][0], racc[mt][1]),
                       fmaxf(racc[mt][2], racc[mt][3])) + bi;
      res_s[(mt * 4 + lq) * 228 + nt * 16 + lrow] = mx;
    }
  }

  // ---- fused attn_proj: A = o rows 0..15 (K=224 spread over head regions)
  short8 Ao[7];
  #pragma unroll
  for (int kt = 0; kt < 7; ++kt) {
    int c = kt * 32 + lq * 8;               // o channel 0..216
    int h2 = (c >= 168) ? 3 : (c >= 112) ? 2 : (c >= 56) ? 1 : 0;
    Ao[kt] = *(const short8*)&u_s[h2 * 9792 + 8640 + lrow * 72 + (c - h2 * 56)];
  }
  for (int i = 0; i < ncnt2; ++i) {
    int nt = nt0 + i;
    f32x4 acc = {0.f, 0.f, 0.f, 0.f};
    #pragma unroll
    for (int kt = 0; kt < 7; ++kt) {
      short8 bw = *(const short8*)(apF + ((nt * 7 + kt) * 64 + lane) * 8);
      acc = __builtin_amdgcn_mfma_f32_16x16x32_bf16(Ao[kt], bw, acc, 0, 0, 0);
    }
    int col2 = nt * 16 + lrow;
    float bi = apb[col2];
    #pragma unroll
    for (int r = 0; r < 4; ++r) {
      float res = res_s[(lq * 4 + r) * 228 + col2];
      size_t token = ((size_t)(b * 64 + nh * 4 + lq)) * 64 + nw * 4 + r;
      hs2[token * 224 + col2] = res + acc[r] + bi;
    }
  }
}

// ------------- fused LN2 + mlp1 + GELU + mlp2 + residual, 32x32x16 MFMA
// (R11/R9 version: lane=channel epilogues, fused multi-tile GEMM1, res
// prefetch, dual GEMM2 accumulators)
template <int NT>
__device__ __forceinline__ void mlp1_tiles(
    int nt0, const short* ln_s, const short* __restrict__ m1F,
    const float* __restrict__ b1, short* hid_s, int nl, int half, int lane) {
  f32x16 acc[NT];
  #pragma unroll
  for (int i = 0; i < NT; ++i)
    #pragma unroll
    for (int r = 0; r < 16; ++r) acc[i][r] = 0.f;
  #pragma unroll
  for (int kt = 0; kt < 14; ++kt) {
    short8 a = *(const short8*)&ln_s[nl * 232 + kt * 16 + half * 8];
    #pragma unroll
    for (int i = 0; i < NT; ++i) {
      short8 bw = *(const short8*)(m1F + ((size_t)((nt0 + i) * 14 + kt) * 64 + lane) * 8);
      acc[i] = __builtin_amdgcn_mfma_f32_32x32x16_bf16(a, bw, acc[i], 0, 0, 0);
    }
  }
  #pragma unroll
  for (int i = 0; i < NT; ++i) {
    int col = (nt0 + i) * 32 + nl;
    float bi = b1[col];
    #pragma unroll
    for (int r = 0; r < 16; ++r) {
      int row = (r & 3) + 8 * (r >> 2) + 4 * half;
      hid_s[row * 904 + col] = f2bf(gelu_fast(acc[i][r] + bi));
    }
  }
}

__global__ __launch_bounds__(512, 4) void mlp_kernel(
    const float* __restrict__ hs2, const float* __restrict__ g2,
    const float* __restrict__ b2, const short* __restrict__ m1F,
    const float* __restrict__ b1, const short* __restrict__ m2F,
    const float* __restrict__ b2b, float* __restrict__ out) {
  __shared__ alignas(16) short ln_s[32 * 232];   // 14,848 B
  __shared__ alignas(16) short hid_s[32 * 904];  // 57,856 B => 72,704 B
  int blk = blockIdx.x;  // 1024 x 32 tokens
  int tid = threadIdx.x;
  size_t base = (size_t)blk * 32 * 224;
  {
    int row = tid >> 4, l = tid & 15;
    const float* rp = hs2 + base + (size_t)row * 224;
    float v[14];
    float s = 0.f;
    #pragma unroll
    for (int c = 0; c < 14; ++c) { v[c] = rp[l + 16 * c]; s += v[c]; }
    #pragma unroll
    for (int off = 8; off; off >>= 1) s += __shfl_xor(s, off, 16);
    float mean = s * (1.f / 224.f);
    float s2 = 0.f;
    #pragma unroll
    for (int c = 0; c < 14; ++c) { float d = v[c] - mean; s2 = fmaf(d, d, s2); }
    #pragma unroll
    for (int off = 8; off; off >>= 1) s2 += __shfl_xor(s2, off, 16);
    float rs = rsqrtf(s2 * (1.f / 224.f) + 1e-6f);
    #pragma unroll
    for (int c = 0; c < 14; ++c) {
      int cc = l + 16 * c;
      ln_s[row * 232 + cc] = f2bf((v[c] - mean) * rs * g2[cc] + b2[cc]);
    }
  }
  __syncthreads();
  int wave = tid >> 6, lane = tid & 63;
  int nl = lane & 31, half = lane >> 5;
  if (wave < 4) mlp1_tiles<4>(wave * 4, ln_s, m1F, b1, hid_s, nl, half, lane);
  else          mlp1_tiles<3>(16 + (wave - 4) * 3, ln_s, m1F, b1, hid_s, nl, half, lane);
  __syncthreads();
  if (wave < 7) {
    int nt = wave;
    int col = nt * 32 + nl;
    float res[16];
    #pragma unroll
    for (int r = 0; r < 16; ++r) {
      int row = (r & 3) + 8 * (r >> 2) + 4 * half;
      res[r] = hs2[base + (size_t)row * 224 + col];
    }
    f32x16 ac0 = {0.f,0.f,0.f,0.f,0.f,0.f,0.f,0.f,0.f,0.f,0.f,0.f,0.f,0.f,0.f,0.f};
    f32x16 ac1 = {0.f,0.f,0.f,0.f,0.f,0.f,0.f,0.f,0.f,0.f,0.f,0.f,0.f,0.f,0.f,0.f};
    #pragma unroll 4
    for (int kt = 0; kt < 56; kt += 2) {
      short8 a0 = *(const short8*)&hid_s[nl * 904 + kt * 16 + half * 8];
      short8 a1 = *(const short8*)&hid_s[nl * 904 + (kt + 1) * 16 + half * 8];
      short8 b0 = *(const short8*)(m2F + ((size_t)(nt * 56 + kt) * 64 + lane) * 8);
      short8 b1 = *(const short8*)(m2F + ((size_t)(nt * 56 + kt + 1) * 64 + lane) * 8);
      ac0 = __builtin_amdgcn_mfma_f32_32x32x16_bf16(a0, b0, ac0, 0, 0, 0);
      ac1 = __builtin_amdgcn_mfma_f32_32x32x16_bf16(a1, b1, ac1, 0, 0, 0);
    }
    float bi = b2b[col];
    #pragma unroll
    for (int r = 0; r < 16; ++r) {
      int row = (r & 3) + 8 * (r >> 2) + 4 * half;
      size_t idx = base + (size_t)row * 224 + col;
      out[idx] = res[r] + ac0[r] + ac1[r] + bi;
    }
  }
}

extern "C" void kernel_launch(void* const* d_in, const int* in_sizes, int n_in,
                              void* d_out, int out_size, void* d_ws, size_t ws_size,
                              hipStream_t stream) {
  const float* x    = (const float*)d_in[0];
  const float* ln1g = (const float*)d_in[1];
  const float* ln1b = (const float*)d_in[2];
  const float* qkvw = (const float*)d_in[3];
  const float* qkvb = (const float*)d_in[4];
  const float* apw  = (const float*)d_in[5];
  const float* apb  = (const float*)d_in[6];
  const float* rpw  = (const float*)d_in[7];
  const float* rpb  = (const float*)d_in[8];
  const float* ln2g = (const float*)d_in[9];
  const float* ln2b = (const float*)d_in[10];
  const float* w1   = (const float*)d_in[11];
  const float* b1   = (const float*)d_in[12];
  const float* w2   = (const float*)d_in[13];
  const float* b2   = (const float*)d_in[14];
  float* out = (float*)d_out;

  short* hs_bf = (short*)d_ws;
  float* hs2   = (float*)((char*)d_ws + 29360128);
  short* wF    = (short*)((char*)d_ws + 73400320);

  cast_w_kernel<<<1024, 256, 0, stream>>>(qkvw, rpw, apw, w1, w2, wF);
  ln1_kernel<<<16384, 256, 0, stream>>>(x, ln1g, ln1b, hs_bf);
  attn_kernel<<<2048, 256, 0, stream>>>(hs_bf, wF, qkvb, wF + 118784, apb,
                                        wF + 90112, rpb, hs2);
  mlp_kernel<<<1024, 512, 0, stream>>>(hs2, ln2g, ln2b, wF + 168960, b1,
                                       wF + 369664, b2, out);
}

// Round 8
// 215.996 us; speedup vs baseline: 1.2755x; 1.0776x over previous
//
#include <hip/hip_runtime.h>
#include <hip/hip_bf16.h>
#include <math.h>

// SAM2 MultiScale Block — round 15: fuse LN1 into attn.
//  - ln1_kernel DELETED. attn stages x (f32) directly: 4 lanes/token, each
//    lane owns 28 channels (7x f32x4, contiguous 112B/lane), quad shfl_xor
//    mean/var, bf16 normalize -> w_s[64][136] (same layout as before).
//  - kills hs_bf roundtrip (29.4MB W + 29.4MB R); attn reads x (58.7MB).
//  - barriers still 2 before qkv; same per-wave regions after.
// mlp/cast identical to R14 (mlp = R11 version).
// DIM=112(K pad 128), DIM_OUT=224, HEADS=4, HD=56, WS=8, QS=2, MLP=896
//
// ws layout (bytes):
//   (hs_bf slot unused since R15)
//   hs2   @ 29,360,128 : 32768x224 f32   = 29,360,128
//   wF    @ 73,400,320 : frag-packed bf16 weights (elems):
//     qkvF 704x128 @ +0       rpF 224x128 @ +90112   apF 224x224 @ +118784
//     m1F  896x224 @ +168960  m2F 224x896 @ +369664  (end 570368)
// 16x16 frag order (qkvF/rpF/apF): (n,k) -> tile=(n/16)*KT+(k/32);
//   flat=(tile*64+lane)*8+j, lane=((k%32)/8)*16+(n%16), j=k%8.
// 32x32 frag order (m1F/m2F): (n,k) -> tile=(n/32)*KT16+(k/16);
//   flat=(tile*64+lane)*8+j, lane=((k%16)/8)*32+(n%32), j=k%8.

#define SCALE_A 0.13363062095621219f  // 56^-0.5

typedef __attribute__((ext_vector_type(8))) short short8;
typedef __attribute__((ext_vector_type(4))) short short4v;
typedef __attribute__((ext_vector_type(4))) float f32x4;
typedef __attribute__((ext_vector_type(16))) float f32x16;

__device__ inline short f2bf(float x) {
  union { float f; unsigned u; } v; v.f = x;
  unsigned r = v.u + 0x7fff + ((v.u >> 16) & 1);
  return (short)(r >> 16);
}
// sigmoid-form tanh-GELU: x * sigmoid(1.59576912*(x + 0.044715 x^3)).
__device__ inline float gelu_fast(float x) {
  float x2 = x * x;
  float p = fmaf(x2, 0.044715f, 1.0f);
  float t = -1.5957691216057308f * x * p;
  return x / (1.0f + __expf(t));
}

// ------------------------------------------- weight cast to frag order
__global__ void cast_w_kernel(const float* __restrict__ qkv_w,
                              const float* __restrict__ rp_w,
                              const float* __restrict__ ap_w,
                              const float* __restrict__ m1_w,
                              const float* __restrict__ m2_w,
                              short* __restrict__ wF) {
  int tid = blockIdx.x * blockDim.x + threadIdx.x;
  int stride = gridDim.x * blockDim.x;
  // qkvF: permuted cols cp = h*176 + cl; cl: [q 0..55|k 56..111|v 112..167|pad]
  for (int e = tid; e < 90112; e += stride) {
    int j = e & 7, lr = (e >> 3) & 15, lqq = (e >> 7) & 3, tile = e >> 9;
    int kt = tile & 3, nt = tile >> 2;
    int cp = nt * 16 + lr;
    int h = cp / 176, cl = cp % 176;
    int k = kt * 32 + lqq * 8 + j;
    float val = 0.f;
    if (k < 112 && cl < 168) {
      int bcol = (cl < 56) ? (h * 56 + cl)
               : (cl < 112) ? (224 + h * 56 + (cl - 56))
                            : (448 + h * 56 + (cl - 112));
      val = qkv_w[k * 672 + bcol];
    }
    wF[e] = f2bf(val);
  }
  for (int e = tid; e < 28672; e += stride) {  // rpF: N=224, KT=4 (16x16)
    int j = e & 7, lr = (e >> 3) & 15, lqq = (e >> 7) & 3, tile = e >> 9;
    int kt = tile & 3, nt = tile >> 2;
    int n = nt * 16 + lr, k = kt * 32 + lqq * 8 + j;
    wF[90112 + e] = (k < 112) ? f2bf(rp_w[k * 224 + n]) : (short)0;
  }
  for (int e = tid; e < 50176; e += stride) {  // apF: N=224, KT=7 (16x16)
    int j = e & 7, lr = (e >> 3) & 15, lqq = (e >> 7) & 3, tile = e >> 9;
    int kt = tile % 7, nt = tile / 7;
    int n = nt * 16 + lr, k = kt * 32 + lqq * 8 + j;
    wF[118784 + e] = f2bf(ap_w[k * 224 + n]);
  }
  for (int e = tid; e < 200704; e += stride) {  // m1F: N=896/32, K=224/16 (32x32)
    int j = e & 7, lane = (e >> 3) & 63, unit = e >> 9;
    int kt = unit % 14, nt = unit / 14;
    int n = nt * 32 + (lane & 31), k = kt * 16 + (lane >> 5) * 8 + j;
    wF[168960 + e] = f2bf(m1_w[k * 896 + n]);
  }
  for (int e = tid; e < 200704; e += stride) {  // m2F: N=224/32, K=896/16 (32x32)
    int j = e & 7, lane = (e >> 3) & 63, unit = e >> 9;
    int kt = unit % 56, nt = unit / 56;
    int n = nt * 32 + (lane & 31), k = kt * 16 + (lane >> 5) * 8 + j;
    wF[369664 + e] = f2bf(m2_w[k * 224 + n]);
  }
}

// --- fused LN1 + windowed attention + attn_proj + res_proj/maxpool, R15
__global__ __launch_bounds__(256, 2) void attn_kernel(
    const float* __restrict__ x, const float* __restrict__ ln1_g,
    const float* __restrict__ ln1_b, const short* __restrict__ qkvF,
    const float* __restrict__ qkv_b, const short* __restrict__ apF,
    const float* __restrict__ apb, const short* __restrict__ rpF,
    const float* __restrict__ rpb, float* __restrict__ hs2) {
  __shared__ alignas(16) short u_s[4 * 9792];   // 78,336 B
  int win = blockIdx.x;                         // 2048
  int nw = win & 15, nh = (win >> 4) & 15, b = win >> 8;
  int tid = threadIdx.x;
  int wave = tid >> 6, lane = tid & 63, lrow = lane & 15, lq = lane >> 4;
  short* w_s  = u_s;                    // [64*136] LN'd tokens (hoist only)
  short* k_s  = u_s + wave * 9792;      // private
  short* vT_s = k_s + 4608;
  short* qp_s = k_s + 8640;             // q -> P -> o(head) region

  // ---- staging + LN1: 4 lanes/token, lane owns 28 contiguous channels
  {
    int part = tid & 3, m = tid >> 2;   // token m, quarter part
    int p = m >> 2, r = m & 3;
    int tr = (p >> 2) * 2 + (r >> 1), tc = (p & 3) * 2 + (r & 1);
    size_t token = ((size_t)(b * 128 + nh * 8 + tr)) * 128 + (nw * 8 + tc);
    const float* xp = x + token * 112 + part * 28;
    f32x4 v[7];
    #pragma unroll
    for (int i = 0; i < 7; ++i) v[i] = *(const f32x4*)(xp + i * 4);
    float s = 0.f;
    #pragma unroll
    for (int i = 0; i < 7; ++i) s += v[i][0] + v[i][1] + v[i][2] + v[i][3];
    s += __shfl_xor(s, 1, 4);
    s += __shfl_xor(s, 2, 4);
    float mean = s * (1.f / 112.f);
    float s2 = 0.f;
    #pragma unroll
    for (int i = 0; i < 7; ++i)
      #pragma unroll
      for (int q = 0; q < 4; ++q) { float d = v[i][q] - mean; s2 = fmaf(d, d, s2); }
    s2 += __shfl_xor(s2, 1, 4);
    s2 += __shfl_xor(s2, 2, 4);
    float rs = rsqrtf(s2 * (1.f / 112.f) + 1e-6f);
    const float* gp = ln1_g + part * 28;
    const float* bp = ln1_b + part * 28;
    #pragma unroll
    for (int i = 0; i < 7; ++i) {
      f32x4 gg = *(const f32x4*)(gp + i * 4);
      f32x4 bb = *(const f32x4*)(bp + i * 4);
      short4v o;
      #pragma unroll
      for (int q = 0; q < 4; ++q)
        o[q] = f2bf((v[i][q] - mean) * rs * gg[q] + bb[q]);
      *(short4v*)&w_s[m * 136 + part * 28 + i * 4] = o;
    }
  }
  // zero pad cols 112..135 (192 threads x short8)
  if (tid < 192) {
    short8 z = {0, 0, 0, 0, 0, 0, 0, 0};
    *(short8*)&w_s[(tid / 3) * 136 + 112 + (tid % 3) * 8] = z;
  }
  __syncthreads();  // staging + LN done

  // hoist A-frags for all 4 M-tiles: 64 VGPR (live through respool!)
  short8 Aw[4][4];
  #pragma unroll
  for (int mt = 0; mt < 4; ++mt)
    #pragma unroll
    for (int kt = 0; kt < 4; ++kt)
      Aw[mt][kt] = *(const short8*)&w_s[(mt * 16 + lrow) * 136 + kt * 32 + lq * 8];
  __syncthreads();  // hoists done; per-wave regions may be written

  // zero pads (per-wave, one short8 store per lane)
  {
    short8 z = {0, 0, 0, 0, 0, 0, 0, 0};
    *(short8*)&k_s[lane * 72 + 56] = z;          // k pad cols 56..63, 64 rows
    if (lane < 16) *(short8*)&qp_s[lane * 72 + 56] = z;  // q pad
  }

  int h = wave;  // head ownership

  // ---- qkv: 11 N-tiles for this head, all 4 M-tiles
  #pragma unroll 2
  for (int t = 0; t < 11; ++t) {
    int cl = t * 16 + lrow;
    f32x4 ac[4] = {{0.f,0.f,0.f,0.f},{0.f,0.f,0.f,0.f},
                   {0.f,0.f,0.f,0.f},{0.f,0.f,0.f,0.f}};
    short8 bw[4];
    #pragma unroll
    for (int kt = 0; kt < 4; ++kt)
      bw[kt] = *(const short8*)(qkvF + (((h * 11 + t) * 4 + kt) * 64 + lane) * 8);
    #pragma unroll
    for (int kt = 0; kt < 4; ++kt)
      #pragma unroll
      for (int mt = 0; mt < 4; ++mt)
        ac[mt] = __builtin_amdgcn_mfma_f32_16x16x32_bf16(Aw[mt][kt], bw[kt], ac[mt], 0, 0, 0);
    if (cl < 56) {
      float bias = qkv_b[h * 56 + cl];
      #pragma unroll
      for (int mt = 0; mt < 4; ++mt) {
        float mx = fmaxf(fmaxf(ac[mt][0], ac[mt][1]),
                         fmaxf(ac[mt][2], ac[mt][3])) + bias;
        qp_s[(mt * 4 + lq) * 72 + cl] = f2bf(mx * SCALE_A);
      }
    } else if (cl < 112) {
      float bias = qkv_b[224 + h * 56 + (cl - 56)];
      #pragma unroll
      for (int mt = 0; mt < 4; ++mt)
        #pragma unroll
        for (int r = 0; r < 4; ++r)
          k_s[(mt * 16 + lq * 4 + r) * 72 + (cl - 56)] = f2bf(ac[mt][r] + bias);
    } else if (cl < 168) {
      float bias = qkv_b[448 + h * 56 + (cl - 112)];
      #pragma unroll
      for (int mt = 0; mt < 4; ++mt) {
        short4v pk = {f2bf(ac[mt][0] + bias), f2bf(ac[mt][1] + bias),
                      f2bf(ac[mt][2] + bias), f2bf(ac[mt][3] + bias)};
        *(short4v*)&vT_s[(cl - 112) * 72 + mt * 16 + lq * 4] = pk;
      }
    }
  }
  // no barrier: same-wave LDS write->read (waitcnt handles it)

  // ---- scores: 16 queries x 64 keys
  short8 aq[2];
  #pragma unroll
  for (int kt = 0; kt < 2; ++kt)
    aq[kt] = *(const short8*)&qp_s[lrow * 72 + kt * 32 + lq * 8];
  f32x4 sc[4];
  #pragma unroll
  for (int t = 0; t < 4; ++t) {
    sc[t][0] = sc[t][1] = sc[t][2] = sc[t][3] = 0.f;
    #pragma unroll
    for (int kt = 0; kt < 2; ++kt) {
      short8 bk = *(const short8*)&k_s[(t * 16 + lrow) * 72 + kt * 32 + lq * 8];
      sc[t] = __builtin_amdgcn_mfma_f32_16x16x32_bf16(aq[kt], bk, sc[t], 0, 0, 0);
    }
  }
  // ---- softmax rows lq*4+r: reduce over t (local) and lrow (16-lane shfl)
  float mr[4], sr[4];
  #pragma unroll
  for (int r = 0; r < 4; ++r)
    mr[r] = fmaxf(fmaxf(sc[0][r], sc[1][r]), fmaxf(sc[2][r], sc[3][r]));
  #pragma unroll
  for (int off = 8; off; off >>= 1)
    #pragma unroll
    for (int r = 0; r < 4; ++r) mr[r] = fmaxf(mr[r], __shfl_xor(mr[r], off, 16));
  #pragma unroll
  for (int r = 0; r < 4; ++r) {
    #pragma unroll
    for (int t = 0; t < 4; ++t) sc[t][r] = __expf(sc[t][r] - mr[r]);
    sr[r] = sc[0][r] + sc[1][r] + sc[2][r] + sc[3][r];
  }
  #pragma unroll
  for (int off = 8; off; off >>= 1)
    #pragma unroll
    for (int r = 0; r < 4; ++r) sr[r] += __shfl_xor(sr[r], off, 16);
  #pragma unroll
  for (int r = 0; r < 4; ++r) sr[r] = 1.f / sr[r];
  // normalized P -> qp_s (q is dead; same-wave write->read, no barrier)
  #pragma unroll
  for (int t = 0; t < 4; ++t)
    #pragma unroll
    for (int r = 0; r < 4; ++r)
      qp_s[(lq * 4 + r) * 72 + t * 16 + lrow] = f2bf(sc[t][r] * sr[r]);

  // ---- PV: all 56 cols; tiles {0,16,32,40}, 4th overlaps (store lrow>=8).
  // P fully consumed into ap[2] registers -> qp_s becomes this head's o.
  short8 ap[2];
  #pragma unroll
  for (int kt = 0; kt < 2; ++kt)
    ap[kt] = *(const short8*)&qp_s[lrow * 72 + kt * 32 + lq * 8];
  #pragma unroll
  for (int ct = 0; ct < 4; ++ct) {
    int c0 = (ct < 3) ? ct * 16 : 40;
    int col = c0 + lrow;
    f32x4 ov = {0.f, 0.f, 0.f, 0.f};
    #pragma unroll
    for (int kt = 0; kt < 2; ++kt) {
      short8 bv = *(const short8*)&vT_s[col * 72 + kt * 32 + lq * 8];
      ov = __builtin_amdgcn_mfma_f32_16x16x32_bf16(ap[kt], bv, ov, 0, 0, 0);
    }
    if (ct < 3 || lrow >= 8) {
      #pragma unroll
      for (int r = 0; r < 4; ++r)
        qp_s[(lq * 4 + r) * 72 + col] = f2bf(ov[r]);  // o (head h), same-wave
    }
  }
  __syncthreads();  // all heads' o ready; all k/vT regions now DEAD

  // ---- fused respool: this wave's aproj N-tiles, all 4 M-tiles via Aw.
  // res_s over dead w_s/k/vT region: f32[16][228] = 14,592 B.
  float* res_s = (float*)u_s;
  int nt0 = (wave < 2) ? wave * 4 : 8 + (wave - 2) * 3;
  int ncnt2 = (wave < 2) ? 4 : 3;
  for (int i = 0; i < ncnt2; ++i) {
    int nt = nt0 + i;
    f32x4 racc[4] = {{0.f,0.f,0.f,0.f},{0.f,0.f,0.f,0.f},
                     {0.f,0.f,0.f,0.f},{0.f,0.f,0.f,0.f}};
    short8 rw[4];
    #pragma unroll
    for (int kt = 0; kt < 4; ++kt)
      rw[kt] = *(const short8*)(rpF + (((nt * 4) + kt) * 64 + lane) * 8);
    #pragma unroll
    for (int kt = 0; kt < 4; ++kt)
      #pragma unroll
      for (int mt = 0; mt < 4; ++mt)
        racc[mt] = __builtin_amdgcn_mfma_f32_16x16x32_bf16(Aw[mt][kt], rw[kt], racc[mt], 0, 0, 0);
    float bi = rpb[nt * 16 + lrow];
    #pragma unroll
    for (int mt = 0; mt < 4; ++mt) {
      float mx = fmaxf(fmaxf(racc[mt][0], racc[mt][1]),
                       fmaxf(racc[mt][2], racc[mt][3])) + bi;
      res_s[(mt * 4 + lq) * 228 + nt * 16 + lrow] = mx;
    }
  }

  // ---- fused attn_proj: A = o rows 0..15 (K=224 spread over head regions)
  short8 Ao[7];
  #pragma unroll
  for (int kt = 0; kt < 7; ++kt) {
    int c = kt * 32 + lq * 8;               // o channel 0..216
    int h2 = (c >= 168) ? 3 : (c >= 112) ? 2 : (c >= 56) ? 1 : 0;
    Ao[kt] = *(const short8*)&u_s[h2 * 9792 + 8640 + lrow * 72 + (c - h2 * 56)];
  }
  for (int i = 0; i < ncnt2; ++i) {
    int nt = nt0 + i;
    f32x4 acc = {0.f, 0.f, 0.f, 0.f};
    #pragma unroll
    for (int kt = 0; kt < 7; ++kt) {
      short8 bw = *(const short8*)(apF + ((nt * 7 + kt) * 64 + lane) * 8);
      acc = __builtin_amdgcn_mfma_f32_16x16x32_bf16(Ao[kt], bw, acc, 0, 0, 0);
    }
    int col2 = nt * 16 + lrow;
    float bi = apb[col2];
    #pragma unroll
    for (int r = 0; r < 4; ++r) {
      float res = res_s[(lq * 4 + r) * 228 + col2];
      size_t token = ((size_t)(b * 64 + nh * 4 + lq)) * 64 + nw * 4 + r;
      hs2[token * 224 + col2] = res + acc[r] + bi;
    }
  }
}

// ------------- fused LN2 + mlp1 + GELU + mlp2 + residual, 32x32x16 MFMA
// (R11/R9 version: lane=channel epilogues, fused multi-tile GEMM1, res
// prefetch, dual GEMM2 accumulators)
template <int NT>
__device__ __forceinline__ void mlp1_tiles(
    int nt0, const short* ln_s, const short* __restrict__ m1F,
    const float* __restrict__ b1, short* hid_s, int nl, int half, int lane) {
  f32x16 acc[NT];
  #pragma unroll
  for (int i = 0; i < NT; ++i)
    #pragma unroll
    for (int r = 0; r < 16; ++r) acc[i][r] = 0.f;
  #pragma unroll
  for (int kt = 0; kt < 14; ++kt) {
    short8 a = *(const short8*)&ln_s[nl * 232 + kt * 16 + half * 8];
    #pragma unroll
    for (int i = 0; i < NT; ++i) {
      short8 bw = *(const short8*)(m1F + ((size_t)((nt0 + i) * 14 + kt) * 64 + lane) * 8);
      acc[i] = __builtin_amdgcn_mfma_f32_32x32x16_bf16(a, bw, acc[i], 0, 0, 0);
    }
  }
  #pragma unroll
  for (int i = 0; i < NT; ++i) {
    int col = (nt0 + i) * 32 + nl;
    float bi = b1[col];
    #pragma unroll
    for (int r = 0; r < 16; ++r) {
      int row = (r & 3) + 8 * (r >> 2) + 4 * half;
      hid_s[row * 904 + col] = f2bf(gelu_fast(acc[i][r] + bi));
    }
  }
}

__global__ __launch_bounds__(512, 4) void mlp_kernel(
    const float* __restrict__ hs2, const float* __restrict__ g2,
    const float* __restrict__ b2, const short* __restrict__ m1F,
    const float* __restrict__ b1, const short* __restrict__ m2F,
    const float* __restrict__ b2b, float* __restrict__ out) {
  __shared__ alignas(16) short ln_s[32 * 232];   // 14,848 B
  __shared__ alignas(16) short hid_s[32 * 904];  // 57,856 B => 72,704 B
  int blk = blockIdx.x;  // 1024 x 32 tokens
  int tid = threadIdx.x;
  size_t base = (size_t)blk * 32 * 224;
  {
    int row = tid >> 4, l = tid & 15;
    const float* rp = hs2 + base + (size_t)row * 224;
    float v[14];
    float s = 0.f;
    #pragma unroll
    for (int c = 0; c < 14; ++c) { v[c] = rp[l + 16 * c]; s += v[c]; }
    #pragma unroll
    for (int off = 8; off; off >>= 1) s += __shfl_xor(s, off, 16);
    float mean = s * (1.f / 224.f);
    float s2 = 0.f;
    #pragma unroll
    for (int c = 0; c < 14; ++c) { float d = v[c] - mean; s2 = fmaf(d, d, s2); }
    #pragma unroll
    for (int off = 8; off; off >>= 1) s2 += __shfl_xor(s2, off, 16);
    float rs = rsqrtf(s2 * (1.f / 224.f) + 1e-6f);
    #pragma unroll
    for (int c = 0; c < 14; ++c) {
      int cc = l + 16 * c;
      ln_s[row * 232 + cc] = f2bf((v[c] - mean) * rs * g2[cc] + b2[cc]);
    }
  }
  __syncthreads();
  int wave = tid >> 6, lane = tid & 63;
  int nl = lane & 31, half = lane >> 5;
  if (wave < 4) mlp1_tiles<4>(wave * 4, ln_s, m1F, b1, hid_s, nl, half, lane);
  else          mlp1_tiles<3>(16 + (wave - 4) * 3, ln_s, m1F, b1, hid_s, nl, half, lane);
  __syncthreads();
  if (wave < 7) {
    int nt = wave;
    int col = nt * 32 + nl;
    float res[16];
    #pragma unroll
    for (int r = 0; r < 16; ++r) {
      int row = (r & 3) + 8 * (r >> 2) + 4 * half;
      res[r] = hs2[base + (size_t)row * 224 + col];
    }
    f32x16 ac0 = {0.f,0.f,0.f,0.f,0.f,0.f,0.f,0.f,0.f,0.f,0.f,0.f,0.f,0.f,0.f,0.f};
    f32x16 ac1 = {0.f,0.f,0.f,0.f,0.f,0.f,0.f,0.f,0.f,0.f,0.f,0.f,0.f,0.f,0.f,0.f};
    #pragma unroll 4
    for (int kt = 0; kt < 56; kt += 2) {
      short8 a0 = *(const short8*)&hid_s[nl * 904 + kt * 16 + half * 8];
      short8 a1 = *(const short8*)&hid_s[nl * 904 + (kt + 1) * 16 + half * 8];
      short8 b0 = *(const short8*)(m2F + ((size_t)(nt * 56 + kt) * 64 + lane) * 8);
      short8 b1 = *(const short8*)(m2F + ((size_t)(nt * 56 + kt + 1) * 64 + lane) * 8);
      ac0 = __builtin_amdgcn_mfma_f32_32x32x16_bf16(a0, b0, ac0, 0, 0, 0);
      ac1 = __builtin_amdgcn_mfma_f32_32x32x16_bf16(a1, b1, ac1, 0, 0, 0);
    }
    float bi = b2b[col];
    #pragma unroll
    for (int r = 0; r < 16; ++r) {
      int row = (r & 3) + 8 * (r >> 2) + 4 * half;
      size_t idx = base + (size_t)row * 224 + col;
      out[idx] = res[r] + ac0[r] + ac1[r] + bi;
    }
  }
}

extern "C" void kernel_launch(void* const* d_in, const int* in_sizes, int n_in,
                              void* d_out, int out_size, void* d_ws, size_t ws_size,
                              hipStream_t stream) {
  const float* x    = (const float*)d_in[0];
  const float* ln1g = (const float*)d_in[1];
  const float* ln1b = (const float*)d_in[2];
  const float* qkvw = (const float*)d_in[3];
  const float* qkvb = (const float*)d_in[4];
  const float* apw  = (const float*)d_in[5];
  const float* apb  = (const float*)d_in[6];
  const float* rpw  = (const float*)d_in[7];
  const float* rpb  = (const float*)d_in[8];
  const float* ln2g = (const float*)d_in[9];
  const float* ln2b = (const float*)d_in[10];
  const float* w1   = (const float*)d_in[11];
  const float* b1   = (const float*)d_in[12];
  const float* w2   = (const float*)d_in[13];
  const float* b2   = (const float*)d_in[14];
  float* out = (float*)d_out;

  float* hs2 = (float*)((char*)d_ws + 29360128);
  short* wF  = (short*)((char*)d_ws + 73400320);

  cast_w_kernel<<<1024, 256, 0, stream>>>(qkvw, rpw, apw, w1, w2, wF);
  attn_kernel<<<2048, 256, 0, stream>>>(x, ln1g, ln1b, wF, qkvb, wF + 118784,
                                        apb, wF + 90112, rpb, hs2);
  mlp_kernel<<<1024, 512, 0, stream>>>(hs2, ln2g, ln2b, wF + 168960, b1,
                                       wF + 369664, b2, out);
}

// Round 9
// 213.693 us; speedup vs baseline: 1.2893x; 1.0108x over previous
//
#include <hip/hip_runtime.h>
#include <hip/hip_bf16.h>
#include <math.h>

// SAM2 MultiScale Block — round 16: VALU/serialization trims.
//  - f2bf -> __float2bfloat16 (HW v_cvt_pk_bf16_f32, RNE; was 4-op bit trick).
//  - attn: respool MFMA+maxpool hoisted ABOVE the post-PV barrier (res in 16
//    VGPR; rpF/Aw only, no LDS deps); res_s write + aproj after barrier.
//  - mlp LN2: lane owns 14 contiguous channels -> 7x float2 loads + 7x b32
//    packed LDS writes (was 14 scalar loads + 14 b16 writes).
// Everything else identical to R15.
// DIM=112(K pad 128), DIM_OUT=224, HEADS=4, HD=56, WS=8, QS=2, MLP=896
//
// ws layout (bytes):
//   hs2   @ 29,360,128 : 32768x224 f32   = 29,360,128
//   wF    @ 73,400,320 : frag-packed bf16 weights (elems):
//     qkvF 704x128 @ +0       rpF 224x128 @ +90112   apF 224x224 @ +118784
//     m1F  896x224 @ +168960  m2F 224x896 @ +369664  (end 570368)
// 16x16 frag order (qkvF/rpF/apF): (n,k) -> tile=(n/16)*KT+(k/32);
//   flat=(tile*64+lane)*8+j, lane=((k%32)/8)*16+(n%16), j=k%8.
// 32x32 frag order (m1F/m2F): (n,k) -> tile=(n/32)*KT16+(k/16);
//   flat=(tile*64+lane)*8+j, lane=((k%16)/8)*32+(n%32), j=k%8.

#define SCALE_A 0.13363062095621219f  // 56^-0.5

typedef __attribute__((ext_vector_type(8))) short short8;
typedef __attribute__((ext_vector_type(4))) short short4v;
typedef __attribute__((ext_vector_type(4))) float f32x4;
typedef __attribute__((ext_vector_type(16))) float f32x16;

__device__ inline short f2bf(float x) {
  __hip_bfloat16 h = __float2bfloat16(x);  // RNE, lowers to v_cvt_pk_bf16_f32
  union { __hip_bfloat16 h; short s; } u; u.h = h;
  return u.s;
}
// sigmoid-form tanh-GELU: x * sigmoid(1.59576912*(x + 0.044715 x^3)).
__device__ inline float gelu_fast(float x) {
  float x2 = x * x;
  float p = fmaf(x2, 0.044715f, 1.0f);
  float t = -1.5957691216057308f * x * p;
  return x / (1.0f + __expf(t));
}

// ------------------------------------------- weight cast to frag order
__global__ void cast_w_kernel(const float* __restrict__ qkv_w,
                              const float* __restrict__ rp_w,
                              const float* __restrict__ ap_w,
                              const float* __restrict__ m1_w,
                              const float* __restrict__ m2_w,
                              short* __restrict__ wF) {
  int tid = blockIdx.x * blockDim.x + threadIdx.x;
  int stride = gridDim.x * blockDim.x;
  // qkvF: permuted cols cp = h*176 + cl; cl: [q 0..55|k 56..111|v 112..167|pad]
  for (int e = tid; e < 90112; e += stride) {
    int j = e & 7, lr = (e >> 3) & 15, lqq = (e >> 7) & 3, tile = e >> 9;
    int kt = tile & 3, nt = tile >> 2;
    int cp = nt * 16 + lr;
    int h = cp / 176, cl = cp % 176;
    int k = kt * 32 + lqq * 8 + j;
    float val = 0.f;
    if (k < 112 && cl < 168) {
      int bcol = (cl < 56) ? (h * 56 + cl)
               : (cl < 112) ? (224 + h * 56 + (cl - 56))
                            : (448 + h * 56 + (cl - 112));
      val = qkv_w[k * 672 + bcol];
    }
    wF[e] = f2bf(val);
  }
  for (int e = tid; e < 28672; e += stride) {  // rpF: N=224, KT=4 (16x16)
    int j = e & 7, lr = (e >> 3) & 15, lqq = (e >> 7) & 3, tile = e >> 9;
    int kt = tile & 3, nt = tile >> 2;
    int n = nt * 16 + lr, k = kt * 32 + lqq * 8 + j;
    wF[90112 + e] = (k < 112) ? f2bf(rp_w[k * 224 + n]) : (short)0;
  }
  for (int e = tid; e < 50176; e += stride) {  // apF: N=224, KT=7 (16x16)
    int j = e & 7, lr = (e >> 3) & 15, lqq = (e >> 7) & 3, tile = e >> 9;
    int kt = tile % 7, nt = tile / 7;
    int n = nt * 16 + lr, k = kt * 32 + lqq * 8 + j;
    wF[118784 + e] = f2bf(ap_w[k * 224 + n]);
  }
  for (int e = tid; e < 200704; e += stride) {  // m1F: N=896/32, K=224/16 (32x32)
    int j = e & 7, lane = (e >> 3) & 63, unit = e >> 9;
    int kt = unit % 14, nt = unit / 14;
    int n = nt * 32 + (lane & 31), k = kt * 16 + (lane >> 5) * 8 + j;
    wF[168960 + e] = f2bf(m1_w[k * 896 + n]);
  }
  for (int e = tid; e < 200704; e += stride) {  // m2F: N=224/32, K=896/16 (32x32)
    int j = e & 7, lane = (e >> 3) & 63, unit = e >> 9;
    int kt = unit % 56, nt = unit / 56;
    int n = nt * 32 + (lane & 31), k = kt * 16 + (lane >> 5) * 8 + j;
    wF[369664 + e] = f2bf(m2_w[k * 224 + n]);
  }
}

// --- fused LN1 + windowed attention + attn_proj + res_proj/maxpool, R16
__global__ __launch_bounds__(256, 2) void attn_kernel(
    const float* __restrict__ x, const float* __restrict__ ln1_g,
    const float* __restrict__ ln1_b, const short* __restrict__ qkvF,
    const float* __restrict__ qkv_b, const short* __restrict__ apF,
    const float* __restrict__ apb, const short* __restrict__ rpF,
    const float* __restrict__ rpb, float* __restrict__ hs2) {
  __shared__ alignas(16) short u_s[4 * 9792];   // 78,336 B
  int win = blockIdx.x;                         // 2048
  int nw = win & 15, nh = (win >> 4) & 15, b = win >> 8;
  int tid = threadIdx.x;
  int wave = tid >> 6, lane = tid & 63, lrow = lane & 15, lq = lane >> 4;
  short* w_s  = u_s;                    // [64*136] LN'd tokens (hoist only)
  short* k_s  = u_s + wave * 9792;      // private
  short* vT_s = k_s + 4608;
  short* qp_s = k_s + 8640;             // q -> P -> o(head) region

  // ---- staging + LN1: 4 lanes/token, lane owns 28 contiguous channels
  {
    int part = tid & 3, m = tid >> 2;   // token m, quarter part
    int p = m >> 2, r = m & 3;
    int tr = (p >> 2) * 2 + (r >> 1), tc = (p & 3) * 2 + (r & 1);
    size_t token = ((size_t)(b * 128 + nh * 8 + tr)) * 128 + (nw * 8 + tc);
    const float* xp = x + token * 112 + part * 28;
    f32x4 v[7];
    #pragma unroll
    for (int i = 0; i < 7; ++i) v[i] = *(const f32x4*)(xp + i * 4);
    float s = 0.f;
    #pragma unroll
    for (int i = 0; i < 7; ++i) s += v[i][0] + v[i][1] + v[i][2] + v[i][3];
    s += __shfl_xor(s, 1, 4);
    s += __shfl_xor(s, 2, 4);
    float mean = s * (1.f / 112.f);
    float s2 = 0.f;
    #pragma unroll
    for (int i = 0; i < 7; ++i)
      #pragma unroll
      for (int q = 0; q < 4; ++q) { float d = v[i][q] - mean; s2 = fmaf(d, d, s2); }
    s2 += __shfl_xor(s2, 1, 4);
    s2 += __shfl_xor(s2, 2, 4);
    float rs = rsqrtf(s2 * (1.f / 112.f) + 1e-6f);
    const float* gp = ln1_g + part * 28;
    const float* bp = ln1_b + part * 28;
    #pragma unroll
    for (int i = 0; i < 7; ++i) {
      f32x4 gg = *(const f32x4*)(gp + i * 4);
      f32x4 bb = *(const f32x4*)(bp + i * 4);
      short4v o;
      #pragma unroll
      for (int q = 0; q < 4; ++q)
        o[q] = f2bf((v[i][q] - mean) * rs * gg[q] + bb[q]);
      *(short4v*)&w_s[m * 136 + part * 28 + i * 4] = o;
    }
  }
  // zero pad cols 112..135 (192 threads x short8)
  if (tid < 192) {
    short8 z = {0, 0, 0, 0, 0, 0, 0, 0};
    *(short8*)&w_s[(tid / 3) * 136 + 112 + (tid % 3) * 8] = z;
  }
  __syncthreads();  // staging + LN done

  // hoist A-frags for all 4 M-tiles: 64 VGPR (live through respool!)
  short8 Aw[4][4];
  #pragma unroll
  for (int mt = 0; mt < 4; ++mt)
    #pragma unroll
    for (int kt = 0; kt < 4; ++kt)
      Aw[mt][kt] = *(const short8*)&w_s[(mt * 16 + lrow) * 136 + kt * 32 + lq * 8];
  __syncthreads();  // hoists done; per-wave regions may be written

  // zero pads (per-wave, one short8 store per lane)
  {
    short8 z = {0, 0, 0, 0, 0, 0, 0, 0};
    *(short8*)&k_s[lane * 72 + 56] = z;          // k pad cols 56..63, 64 rows
    if (lane < 16) *(short8*)&qp_s[lane * 72 + 56] = z;  // q pad
  }

  int h = wave;  // head ownership

  // ---- qkv: 11 N-tiles for this head, all 4 M-tiles
  #pragma unroll 2
  for (int t = 0; t < 11; ++t) {
    int cl = t * 16 + lrow;
    f32x4 ac[4] = {{0.f,0.f,0.f,0.f},{0.f,0.f,0.f,0.f},
                   {0.f,0.f,0.f,0.f},{0.f,0.f,0.f,0.f}};
    short8 bw[4];
    #pragma unroll
    for (int kt = 0; kt < 4; ++kt)
      bw[kt] = *(const short8*)(qkvF + (((h * 11 + t) * 4 + kt) * 64 + lane) * 8);
    #pragma unroll
    for (int kt = 0; kt < 4; ++kt)
      #pragma unroll
      for (int mt = 0; mt < 4; ++mt)
        ac[mt] = __builtin_amdgcn_mfma_f32_16x16x32_bf16(Aw[mt][kt], bw[kt], ac[mt], 0, 0, 0);
    if (cl < 56) {
      float bias = qkv_b[h * 56 + cl];
      #pragma unroll
      for (int mt = 0; mt < 4; ++mt) {
        float mx = fmaxf(fmaxf(ac[mt][0], ac[mt][1]),
                         fmaxf(ac[mt][2], ac[mt][3])) + bias;
        qp_s[(mt * 4 + lq) * 72 + cl] = f2bf(mx * SCALE_A);
      }
    } else if (cl < 112) {
      float bias = qkv_b[224 + h * 56 + (cl - 56)];
      #pragma unroll
      for (int mt = 0; mt < 4; ++mt)
        #pragma unroll
        for (int r = 0; r < 4; ++r)
          k_s[(mt * 16 + lq * 4 + r) * 72 + (cl - 56)] = f2bf(ac[mt][r] + bias);
    } else if (cl < 168) {
      float bias = qkv_b[448 + h * 56 + (cl - 112)];
      #pragma unroll
      for (int mt = 0; mt < 4; ++mt) {
        short4v pk = {f2bf(ac[mt][0] + bias), f2bf(ac[mt][1] + bias),
                      f2bf(ac[mt][2] + bias), f2bf(ac[mt][3] + bias)};
        *(short4v*)&vT_s[(cl - 112) * 72 + mt * 16 + lq * 4] = pk;
      }
    }
  }
  // no barrier: same-wave LDS write->read (waitcnt handles it)

  // ---- scores: 16 queries x 64 keys
  short8 aq[2];
  #pragma unroll
  for (int kt = 0; kt < 2; ++kt)
    aq[kt] = *(const short8*)&qp_s[lrow * 72 + kt * 32 + lq * 8];
  f32x4 sc[4];
  #pragma unroll
  for (int t = 0; t < 4; ++t) {
    sc[t][0] = sc[t][1] = sc[t][2] = sc[t][3] = 0.f;
    #pragma unroll
    for (int kt = 0; kt < 2; ++kt) {
      short8 bk = *(const short8*)&k_s[(t * 16 + lrow) * 72 + kt * 32 + lq * 8];
      sc[t] = __builtin_amdgcn_mfma_f32_16x16x32_bf16(aq[kt], bk, sc[t], 0, 0, 0);
    }
  }
  // ---- softmax rows lq*4+r: reduce over t (local) and lrow (16-lane shfl)
  float mr[4], sr[4];
  #pragma unroll
  for (int r = 0; r < 4; ++r)
    mr[r] = fmaxf(fmaxf(sc[0][r], sc[1][r]), fmaxf(sc[2][r], sc[3][r]));
  #pragma unroll
  for (int off = 8; off; off >>= 1)
    #pragma unroll
    for (int r = 0; r < 4; ++r) mr[r] = fmaxf(mr[r], __shfl_xor(mr[r], off, 16));
  #pragma unroll
  for (int r = 0; r < 4; ++r) {
    #pragma unroll
    for (int t = 0; t < 4; ++t) sc[t][r] = __expf(sc[t][r] - mr[r]);
    sr[r] = sc[0][r] + sc[1][r] + sc[2][r] + sc[3][r];
  }
  #pragma unroll
  for (int off = 8; off; off >>= 1)
    #pragma unroll
    for (int r = 0; r < 4; ++r) sr[r] += __shfl_xor(sr[r], off, 16);
  #pragma unroll
  for (int r = 0; r < 4; ++r) sr[r] = 1.f / sr[r];
  // normalized P -> qp_s (q is dead; same-wave write->read, no barrier)
  #pragma unroll
  for (int t = 0; t < 4; ++t)
    #pragma unroll
    for (int r = 0; r < 4; ++r)
      qp_s[(lq * 4 + r) * 72 + t * 16 + lrow] = f2bf(sc[t][r] * sr[r]);

  // ---- PV: all 56 cols; tiles {0,16,32,40}, 4th overlaps (store lrow>=8).
  // P fully consumed into ap[2] registers -> qp_s becomes this head's o.
  short8 ap[2];
  #pragma unroll
  for (int kt = 0; kt < 2; ++kt)
    ap[kt] = *(const short8*)&qp_s[lrow * 72 + kt * 32 + lq * 8];
  #pragma unroll
  for (int ct = 0; ct < 4; ++ct) {
    int c0 = (ct < 3) ? ct * 16 : 40;
    int col = c0 + lrow;
    f32x4 ov = {0.f, 0.f, 0.f, 0.f};
    #pragma unroll
    for (int kt = 0; kt < 2; ++kt) {
      short8 bv = *(const short8*)&vT_s[col * 72 + kt * 32 + lq * 8];
      ov = __builtin_amdgcn_mfma_f32_16x16x32_bf16(ap[kt], bv, ov, 0, 0, 0);
    }
    if (ct < 3 || lrow >= 8) {
      #pragma unroll
      for (int r = 0; r < 4; ++r)
        qp_s[(lq * 4 + r) * 72 + col] = f2bf(ov[r]);  // o (head h), same-wave
    }
  }

  // ---- respool compute PRE-barrier (Aw regs + rpF from L2; no LDS deps).
  // res kept in 16 VGPR across the barrier; statically indexed (unroll+guard).
  int nt0 = (wave < 2) ? wave * 4 : 8 + (wave - 2) * 3;
  int ncnt2 = (wave < 2) ? 4 : 3;
  float resv[4][4];
  #pragma unroll
  for (int i = 0; i < 4; ++i) {
    if (i < ncnt2) {  // wave-uniform guard
      int nt = nt0 + i;
      f32x4 racc[4] = {{0.f,0.f,0.f,0.f},{0.f,0.f,0.f,0.f},
                       {0.f,0.f,0.f,0.f},{0.f,0.f,0.f,0.f}};
      short8 rw[4];
      #pragma unroll
      for (int kt = 0; kt < 4; ++kt)
        rw[kt] = *(const short8*)(rpF + (((nt * 4) + kt) * 64 + lane) * 8);
      #pragma unroll
      for (int kt = 0; kt < 4; ++kt)
        #pragma unroll
        for (int mt = 0; mt < 4; ++mt)
          racc[mt] = __builtin_amdgcn_mfma_f32_16x16x32_bf16(Aw[mt][kt], rw[kt], racc[mt], 0, 0, 0);
      float bi = rpb[nt * 16 + lrow];
      #pragma unroll
      for (int mt = 0; mt < 4; ++mt)
        resv[i][mt] = fmaxf(fmaxf(racc[mt][0], racc[mt][1]),
                            fmaxf(racc[mt][2], racc[mt][3])) + bi;
    }
  }
  __syncthreads();  // all heads' o ready; all k/vT regions now DEAD

  // res -> res_s f32[16][228] over dead w_s/k/vT region (same-wave reads later)
  float* res_s = (float*)u_s;
  #pragma unroll
  for (int i = 0; i < 4; ++i) {
    if (i < ncnt2) {
      int nt = nt0 + i;
      #pragma unroll
      for (int mt = 0; mt < 4; ++mt)
        res_s[(mt * 4 + lq) * 228 + nt * 16 + lrow] = resv[i][mt];
    }
  }

  // ---- fused attn_proj: A = o rows 0..15 (K=224 spread over head regions)
  short8 Ao[7];
  #pragma unroll
  for (int kt = 0; kt < 7; ++kt) {
    int c = kt * 32 + lq * 8;               // o channel 0..216
    int h2 = (c >= 168) ? 3 : (c >= 112) ? 2 : (c >= 56) ? 1 : 0;
    Ao[kt] = *(const short8*)&u_s[h2 * 9792 + 8640 + lrow * 72 + (c - h2 * 56)];
  }
  for (int i = 0; i < ncnt2; ++i) {
    int nt = nt0 + i;
    f32x4 acc = {0.f, 0.f, 0.f, 0.f};
    #pragma unroll
    for (int kt = 0; kt < 7; ++kt) {
      short8 bw = *(const short8*)(apF + ((nt * 7 + kt) * 64 + lane) * 8);
      acc = __builtin_amdgcn_mfma_f32_16x16x32_bf16(Ao[kt], bw, acc, 0, 0, 0);
    }
    int col2 = nt * 16 + lrow;
    float bi = apb[col2];
    #pragma unroll
    for (int r = 0; r < 4; ++r) {
      float res = res_s[(lq * 4 + r) * 228 + col2];
      size_t token = ((size_t)(b * 64 + nh * 4 + lq)) * 64 + nw * 4 + r;
      hs2[token * 224 + col2] = res + acc[r] + bi;
    }
  }
}

// ------------- fused LN2 + mlp1 + GELU + mlp2 + residual, 32x32x16 MFMA
template <int NT>
__device__ __forceinline__ void mlp1_tiles(
    int nt0, const short* ln_s, const short* __restrict__ m1F,
    const float* __restrict__ b1, short* hid_s, int nl, int half, int lane) {
  f32x16 acc[NT];
  #pragma unroll
  for (int i = 0; i < NT; ++i)
    #pragma unroll
    for (int r = 0; r < 16; ++r) acc[i][r] = 0.f;
  #pragma unroll
  for (int kt = 0; kt < 14; ++kt) {
    short8 a = *(const short8*)&ln_s[nl * 232 + kt * 16 + half * 8];
    #pragma unroll
    for (int i = 0; i < NT; ++i) {
      short8 bw = *(const short8*)(m1F + ((size_t)((nt0 + i) * 14 + kt) * 64 + lane) * 8);
      acc[i] = __builtin_amdgcn_mfma_f32_32x32x16_bf16(a, bw, acc[i], 0, 0, 0);
    }
  }
  #pragma unroll
  for (int i = 0; i < NT; ++i) {
    int col = (nt0 + i) * 32 + nl;
    float bi = b1[col];
    #pragma unroll
    for (int r = 0; r < 16; ++r) {
      int row = (r & 3) + 8 * (r >> 2) + 4 * half;
      hid_s[row * 904 + col] = f2bf(gelu_fast(acc[i][r] + bi));
    }
  }
}

__global__ __launch_bounds__(512, 4) void mlp_kernel(
    const float* __restrict__ hs2, const float* __restrict__ g2,
    const float* __restrict__ b2, const short* __restrict__ m1F,
    const float* __restrict__ b1, const short* __restrict__ m2F,
    const float* __restrict__ b2b, float* __restrict__ out) {
  __shared__ alignas(16) short ln_s[32 * 232];   // 14,848 B
  __shared__ alignas(16) short hid_s[32 * 904];  // 57,856 B => 72,704 B
  int blk = blockIdx.x;  // 1024 x 32 tokens
  int tid = threadIdx.x;
  size_t base = (size_t)blk * 32 * 224;
  {
    // LN2: lane owns 14 CONTIGUOUS channels; 7x float2 loads, 7x b32 writes
    int row = tid >> 4, l = tid & 15;
    const float* rp = hs2 + base + (size_t)row * 224 + l * 14;
    float v[14];
    float s = 0.f;
    #pragma unroll
    for (int c = 0; c < 7; ++c) {
      float2 t = *(const float2*)(rp + 2 * c);
      v[2 * c] = t.x; v[2 * c + 1] = t.y;
      s += t.x + t.y;
    }
    #pragma unroll
    for (int off = 8; off; off >>= 1) s += __shfl_xor(s, off, 16);
    float mean = s * (1.f / 224.f);
    float s2 = 0.f;
    #pragma unroll
    for (int c = 0; c < 14; ++c) { float d = v[c] - mean; s2 = fmaf(d, d, s2); }
    #pragma unroll
    for (int off = 8; off; off >>= 1) s2 += __shfl_xor(s2, off, 16);
    float rs = rsqrtf(s2 * (1.f / 224.f) + 1e-6f);
    const float* gp = g2 + l * 14;
    const float* bp = b2 + l * 14;
    #pragma unroll
    for (int c = 0; c < 7; ++c) {
      float2 gg = *(const float2*)(gp + 2 * c);
      float2 bb = *(const float2*)(bp + 2 * c);
      unsigned lo = (unsigned short)f2bf((v[2 * c] - mean) * rs * gg.x + bb.x);
      unsigned hi = (unsigned short)f2bf((v[2 * c + 1] - mean) * rs * gg.y + bb.y);
      *(unsigned*)&ln_s[row * 232 + l * 14 + 2 * c] = lo | (hi << 16);
    }
  }
  __syncthreads();
  int wave = tid >> 6, lane = tid & 63;
  int nl = lane & 31, half = lane >> 5;
  if (wave < 4) mlp1_tiles<4>(wave * 4, ln_s, m1F, b1, hid_s, nl, half, lane);
  else          mlp1_tiles<3>(16 + (wave - 4) * 3, ln_s, m1F, b1, hid_s, nl, half, lane);
  __syncthreads();
  if (wave < 7) {
    int nt = wave;
    int col = nt * 32 + nl;
    float res[16];
    #pragma unroll
    for (int r = 0; r < 16; ++r) {
      int row = (r & 3) + 8 * (r >> 2) + 4 * half;
      res[r] = hs2[base + (size_t)row * 224 + col];
    }
    f32x16 ac0 = {0.f,0.f,0.f,0.f,0.f,0.f,0.f,0.f,0.f,0.f,0.f,0.f,0.f,0.f,0.f,0.f};
    f32x16 ac1 = {0.f,0.f,0.f,0.f,0.f,0.f,0.f,0.f,0.f,0.f,0.f,0.f,0.f,0.f,0.f,0.f};
    #pragma unroll 4
    for (int kt = 0; kt < 56; kt += 2) {
      short8 a0 = *(const short8*)&hid_s[nl * 904 + kt * 16 + half * 8];
      short8 a1 = *(const short8*)&hid_s[nl * 904 + (kt + 1) * 16 + half * 8];
      short8 b0 = *(const short8*)(m2F + ((size_t)(nt * 56 + kt) * 64 + lane) * 8);
      short8 b1 = *(const short8*)(m2F + ((size_t)(nt * 56 + kt + 1) * 64 + lane) * 8);
      ac0 = __builtin_amdgcn_mfma_f32_32x32x16_bf16(a0, b0, ac0, 0, 0, 0);
      ac1 = __builtin_amdgcn_mfma_f32_32x32x16_bf16(a1, b1, ac1, 0, 0, 0);
    }
    float bi = b2b[col];
    #pragma unroll
    for (int r = 0; r < 16; ++r) {
      int row = (r & 3) + 8 * (r >> 2) + 4 * half;
      size_t idx = base + (size_t)row * 224 + col;
      out[idx] = res[r] + ac0[r] + ac1[r] + bi;
    }
  }
}

extern "C" void kernel_launch(void* const* d_in, const int* in_sizes, int n_in,
                              void* d_out, int out_size, void* d_ws, size_t ws_size,
                              hipStream_t stream) {
  const float* x    = (const float*)d_in[0];
  const float* ln1g = (const float*)d_in[1];
  const float* ln1b = (const float*)d_in[2];
  const float* qkvw = (const float*)d_in[3];
  const float* qkvb = (const float*)d_in[4];
  const float* apw  = (const float*)d_in[5];
  const float* apb  = (const float*)d_in[6];
  const float* rpw  = (const float*)d_in[7];
  const float* rpb  = (const float*)d_in[8];
  const float* ln2g = (const float*)d_in[9];
  const float* ln2b = (const float*)d_in[10];
  const float* w1   = (const float*)d_in[11];
  const float* b1   = (const float*)d_in[12];
  const float* w2   = (const float*)d_in[13];
  const float* b2   = (const float*)d_in[14];
  float* out = (float*)d_out;

  float* hs2 = (float*)((char*)d_ws + 29360128);
  short* wF  = (short*)((char*)d_ws + 73400320);

  cast_w_kernel<<<1024, 256, 0, stream>>>(qkvw, rpw, apw, w1, w2, wF);
  attn_kernel<<<2048, 256, 0, stream>>>(x, ln1g, ln1b, wF, qkvb, wF + 118784,
                                        apb, wF + 90112, rpb, hs2);
  mlp_kernel<<<1024, 512, 0, stream>>>(hs2, ln2g, ln2b, wF + 168960, b1,
                                       wF + 369664, b2, out);
}